// Round 8
// baseline (533.638 us; speedup 1.0000x reference)
//
#include <hip/hip_runtime.h>
#include <math.h>

// Problem constants
#define BB 4
#define TT 2048
#define DD 1024
#define HH 4
#define DK 256
#define DV 256
#define RR 8192
#define CHK 64
#define NCHK 32
#define SS ((size_t)RR * DD)

typedef __bf16 bf16x8 __attribute__((ext_vector_type(8)));
typedef float f32x4 __attribute__((ext_vector_type(4)));

static __device__ inline unsigned short f2bf(float f) {
  unsigned int u = __float_as_uint(f);
  unsigned int r = (u + 0x7fffu + ((u >> 16) & 1u)) >> 16;
  return (unsigned short)r;
}
static __device__ inline float bf2f(unsigned short h) {
  return __uint_as_float(((unsigned int)h) << 16);
}

// async global->LDS, 16B per lane; dest = wave-uniform base + lane*16
static __device__ __forceinline__ void gload16(const unsigned short* g,
                                               unsigned short* l) {
  __builtin_amdgcn_global_load_lds(
      (const __attribute__((address_space(1))) void*)g,
      (__attribute__((address_space(3))) void*)l, 16, 0, 0);
}

// ---------------------------------------------------------------------------
// LayerNorm: one block (256 thr) per row of D=1024. f32 in -> bf16 out.
// ---------------------------------------------------------------------------
__global__ __launch_bounds__(256) void ln_kernel(const float* __restrict__ x,
                                                 const float* __restrict__ w,
                                                 const float* __restrict__ b,
                                                 unsigned short* __restrict__ yb) {
  int row = blockIdx.x;
  const float* xr = x + (size_t)row * DD;
  unsigned short* ybr = yb + (size_t)row * DD;
  int tid = threadIdx.x;

  float4 v = ((const float4*)xr)[tid];
  float s = v.x + v.y + v.z + v.w;
  float ss = v.x * v.x + v.y * v.y + v.z * v.z + v.w * v.w;
#pragma unroll
  for (int o = 32; o > 0; o >>= 1) {
    s += __shfl_down(s, o);
    ss += __shfl_down(ss, o);
  }
  __shared__ float ls[4], lss[4];
  int wid = tid >> 6;
  if ((tid & 63) == 0) { ls[wid] = s; lss[wid] = ss; }
  __syncthreads();
  float sum = ls[0] + ls[1] + ls[2] + ls[3];
  float sumsq = lss[0] + lss[1] + lss[2] + lss[3];
  float mu = sum * (1.0f / DD);
  float var = sumsq * (1.0f / DD) - mu * mu;
  float rs = rsqrtf(var + 1e-5f);

  float4 wv = ((const float4*)w)[tid];
  float4 bv = ((const float4*)b)[tid];
  ushort4 ob;
  ob.x = f2bf((v.x - mu) * rs * wv.x + bv.x);
  ob.y = f2bf((v.y - mu) * rs * wv.y + bv.y);
  ob.z = f2bf((v.z - mu) * rs * wv.z + bv.z);
  ob.w = f2bf((v.w - mu) * rs * wv.w + bv.w);
  ((ushort4*)ybr)[tid] = ob;
}

// ---------------------------------------------------------------------------
// Weight transpose + cast: W [K,N] f32 -> Wt [N,K] bf16
// ---------------------------------------------------------------------------
__global__ __launch_bounds__(256) void transpose_cast(const float* __restrict__ W,
                                                      unsigned short* __restrict__ Wt,
                                                      int K, int N) {
  __shared__ float t[32][33];
  int k0 = blockIdx.y * 32, n0 = blockIdx.x * 32;
  int tid = threadIdx.x;
  int tx = tid & 31, ty = tid >> 5;  // ty 0..7
#pragma unroll
  for (int i = 0; i < 4; ++i)
    t[ty + i * 8][tx] = W[(size_t)(k0 + ty + i * 8) * N + n0 + tx];
  __syncthreads();
#pragma unroll
  for (int i = 0; i < 4; ++i)
    Wt[(size_t)(n0 + ty + i * 8) * K + k0 + tx] = f2bf(t[tx][ty + i * 8]);
}

// ---------------------------------------------------------------------------
// 256x256 bf16 MFMA GEMM, BK=64, 512 threads (8 waves, 2M x 4N), double-
// buffered 128KB LDS, counted-vmcnt pipeline (raw s_barrier, no vmcnt(0)
// drain in the main loop), XOR-swizzled LDS, XCD block swizzle, setprio(T5).
// EPI: 0 none, 2 +bias,(leaky)^2, 3 +res, 4 +bias+res,
//      5 proj fan-out: write bf16 to Cv[(n>>10)*SS + m*1024 + (n&1023)]
// ---------------------------------------------------------------------------
template <int EPI, int OUTBF>
__global__ __launch_bounds__(512) void gemm256(
    const unsigned short* __restrict__ A,   // [M,K] bf16
    const unsigned short* __restrict__ Bt,  // [N,K] bf16
    const float* __restrict__ bias, const float* __restrict__ Res,
    void* __restrict__ Cv, int M, int N, int K) {
  __shared__ unsigned short As[2][256 * 64];  // 32KB each buf
  __shared__ unsigned short Bs[2][256 * 64];
  int tid = threadIdx.x;
  // XCD-aware swizzle (nwg % 8 == 0)
  int nwg = gridDim.x * gridDim.y;
  int wg = blockIdx.y * gridDim.x + blockIdx.x;
  int cpx = nwg >> 3;
  wg = (wg & 7) * cpx + (wg >> 3);
  int m0 = (wg / gridDim.x) * 256, n0 = (wg % gridDim.x) * 256;
  int lane = tid & 63;
  int w64 = tid & 448;  // wave*64 (512 threads)
  int wid = tid >> 6;   // 0..7
  int wm = (wid >> 2) * 128;  // wave M offset (2 rows of waves)
  int wn = (wid & 3) * 64;    // wave N offset (4 cols of waves)
  int fr = lane & 15, fq = lane >> 4;

  f32x4 acc[8][4] = {};

  auto STAGE = [&](int buf, int k0) {
#pragma unroll
    for (int j = 0; j < 4; ++j) {
      int gl = j * 512 + tid;          // granule 0..2047 (256 rows x 8)
      int row = gl >> 3;
      int gs = (gl & 7) ^ (row & 7);   // inverse-swizzled source granule
      gload16(&A[(size_t)(m0 + row) * K + k0 + gs * 8],
              &As[buf][(size_t)(j * 512 + w64) * 8]);
    }
#pragma unroll
    for (int j = 0; j < 4; ++j) {
      int gl = j * 512 + tid;
      int row = gl >> 3;
      int gs = (gl & 7) ^ (row & 7);
      gload16(&Bt[(size_t)(n0 + row) * K + k0 + gs * 8],
              &Bs[buf][(size_t)(j * 512 + w64) * 8]);
    }
  };

  int nt = K >> 6;  // K-tiles (assumes K % 64 == 0, nt >= 2)

  // prologue: stage tiles 0,1; wait for tile 0 (8 own loads remain = tile 1)
  STAGE(0, 0);
  STAGE(1, 64);
  asm volatile("s_waitcnt vmcnt(8)" ::: "memory");
  __builtin_amdgcn_sched_barrier(0);
  __builtin_amdgcn_s_barrier();
  __builtin_amdgcn_sched_barrier(0);

  for (int t = 0; t < nt; ++t) {
    int cur = t & 1;
    const unsigned short* Ab = &As[cur][0];
    const unsigned short* Bb = &Bs[cur][0];
    // compute 64 MFMA from buf[cur]
#pragma unroll
    for (int ks = 0; ks < 2; ++ks) {
      bf16x8 af[8], bv[4];
#pragma unroll
      for (int i = 0; i < 8; ++i) {
        int ra = wm + i * 16 + fr;
        af[i] = *(const bf16x8*)&Ab[ra * 64 + (((ks * 4 + fq) ^ (ra & 7)) * 8)];
      }
#pragma unroll
      for (int j = 0; j < 4; ++j) {
        int rb = wn + j * 16 + fr;
        bv[j] = *(const bf16x8*)&Bb[rb * 64 + (((ks * 4 + fq) ^ (rb & 7)) * 8)];
      }
      __builtin_amdgcn_s_setprio(1);
#pragma unroll
      for (int i = 0; i < 8; ++i)
#pragma unroll
        for (int j = 0; j < 4; ++j)
          acc[i][j] = __builtin_amdgcn_mfma_f32_16x16x32_bf16(af[i], bv[j],
                                                              acc[i][j], 0, 0, 0);
      __builtin_amdgcn_s_setprio(0);
    }
    __builtin_amdgcn_sched_barrier(0);
    __builtin_amdgcn_s_barrier();  // all waves done reading buf[cur]
    __builtin_amdgcn_sched_barrier(0);
    if (t + 2 < nt) {
      STAGE(cur, (t + 2) * 64);  // overwrite freed buffer; tile t+1 loads older
      asm volatile("s_waitcnt vmcnt(8)" ::: "memory");  // tile t+1 resident
      __builtin_amdgcn_sched_barrier(0);
      __builtin_amdgcn_s_barrier();
      __builtin_amdgcn_sched_barrier(0);
    } else if (t + 1 < nt) {
      asm volatile("s_waitcnt vmcnt(0)" ::: "memory");  // last tile resident
      __builtin_amdgcn_sched_barrier(0);
      __builtin_amdgcn_s_barrier();
      __builtin_amdgcn_sched_barrier(0);
    }
  }

  // epilogue: C/D layout col=lane&15, row=(lane>>4)*4+r
  int col = lane & 15;
  int rbase = (lane >> 4) * 4;
#pragma unroll
  for (int i = 0; i < 8; ++i) {
#pragma unroll
    for (int j = 0; j < 4; ++j) {
      int n = n0 + wn + j * 16 + col;
      float bvv = (EPI == 2 || EPI == 4) ? bias[n] : 0.0f;
#pragma unroll
      for (int r = 0; r < 4; ++r) {
        int m = m0 + wm + i * 16 + rbase + r;
        float vv = acc[i][j][r] + bvv;
        if (EPI == 2) {
          float t2 = vv > 0.0f ? vv : 0.01f * vv;
          vv = t2 * t2;
        }
        if (EPI == 3 || EPI == 4) vv += Res[(size_t)m * N + n];
        if (EPI == 5) {
          ((unsigned short*)Cv)[(size_t)(n >> 10) * SS + (size_t)m * 1024 +
                                (n & 1023)] = f2bf(vv);
        } else if (OUTBF) {
          ((unsigned short*)Cv)[(size_t)m * N + n] = f2bf(vv);
        } else {
          ((float*)Cv)[(size_t)m * N + n] = vv;
        }
      }
    }
  }
}

// ---------------------------------------------------------------------------
// Low-rank forget gate -> LOG gate gk = log_sigmoid(z)/16 (bf16 in/out)
// ---------------------------------------------------------------------------
__global__ __launch_bounds__(256) void gk_kernel(const unsigned short* __restrict__ xn,
                                                 const float* __restrict__ Wgk1,
                                                 const float* __restrict__ Wgk2,
                                                 const float* __restrict__ bgk2,
                                                 unsigned short* __restrict__ gk) {
  int row = blockIdx.x;
  const unsigned short* xr = xn + (size_t)row * DD;
  int tid = threadIdx.x;

  float t16[16];
#pragma unroll
  for (int j = 0; j < 16; ++j) t16[j] = 0.0f;

#pragma unroll
  for (int dd = 0; dd < 4; ++dd) {
    int d = tid + dd * 256;
    float xv = bf2f(xr[d]);
    const float4* wrow = (const float4*)(Wgk1 + (size_t)d * 16);
#pragma unroll
    for (int q = 0; q < 4; ++q) {
      float4 wq = wrow[q];
      t16[q * 4 + 0] += xv * wq.x;
      t16[q * 4 + 1] += xv * wq.y;
      t16[q * 4 + 2] += xv * wq.z;
      t16[q * 4 + 3] += xv * wq.w;
    }
  }
#pragma unroll
  for (int j = 0; j < 16; ++j) {
    float s = t16[j];
#pragma unroll
    for (int o = 32; o > 0; o >>= 1) s += __shfl_down(s, o);
    t16[j] = s;
  }
  __shared__ float tmp[4][16];
  __shared__ float tf[16];
  int wid = tid >> 6;
  if ((tid & 63) == 0) {
#pragma unroll
    for (int j = 0; j < 16; ++j) tmp[wid][j] = t16[j];
  }
  __syncthreads();
  if (tid < 16) tf[tid] = tmp[0][tid] + tmp[1][tid] + tmp[2][tid] + tmp[3][tid];
  __syncthreads();

  float tl[16];
#pragma unroll
  for (int j = 0; j < 16; ++j) tl[j] = tf[j];

#pragma unroll
  for (int jj = 0; jj < 4; ++jj) {
    int n = tid * 4 + jj;
    float z = bgk2[n];
#pragma unroll
    for (int j = 0; j < 16; ++j) z += tl[j] * Wgk2[j * 1024 + n];
    float ls = fminf(z, 0.0f) - log1pf(expf(-fabsf(z)));
    gk[(size_t)row * 1024 + n] = f2bf(ls * (1.0f / 16.0f));
  }
}

// ---------------------------------------------------------------------------
// gate_chunk: per (b,h,chunk) block, 256 thr (one dk col each), bf16 in-place:
// q <- q*exp(cum)*scale; k <- k*exp(-cum); ebC = exp(cum_end) out (f32).
// ---------------------------------------------------------------------------
__global__ __launch_bounds__(256) void gate_chunk(const unsigned short* __restrict__ gk,
                                                  unsigned short* __restrict__ q,
                                                  unsigned short* __restrict__ k,
                                                  float* __restrict__ ebC) {
  int bid = blockIdx.x;
  int c = bid & 31;
  int h = (bid >> 5) & 3;
  int b = bid >> 7;
  int tid = threadIdx.x;
  size_t base = ((size_t)b * TT + c * CHK) * 1024 + h * 256 + tid;

  const float scale = 0.0625f;
  float cum = 0.0f;
  for (int t = 0; t < CHK; ++t) {
    size_t a = base + (size_t)t * 1024;
    cum += bf2f(gk[a]);
    q[a] = f2bf(bf2f(q[a]) * expf(cum) * scale);
    k[a] = f2bf(bf2f(k[a]) * expf(-cum));
  }
  ebC[((b * 4 + h) * NCHK + c) * 256 + tid] = expf(cum);
}

// ---------------------------------------------------------------------------
// trans_kernel: [B*T, H*256] slice -> T-major [bh][256][2048]; WITHE folds ebC
// ---------------------------------------------------------------------------
template <int WITHE>
__global__ __launch_bounds__(256) void trans_kernel(const unsigned short* __restrict__ in,
                                                    const float* __restrict__ ebC,
                                                    unsigned short* __restrict__ outT) {
  __shared__ unsigned short T[64][68];
  int bid = blockIdx.x;
  int dkt = bid & 3;
  int ct = (bid >> 2) & 31;
  int bh = bid >> 7;
  int b = bh >> 2, h = bh & 3;
  int tid = threadIdx.x;
  int r = tid >> 4;            // 0..15
  int c4 = (tid & 15) * 4;
  size_t srcbase = ((size_t)b * TT + ct * 64) * 1024 + h * 256 + dkt * 64;
#pragma unroll
  for (int i = 0; i < 4; ++i)
    *(ushort4*)&T[r + i * 16][c4] =
        *(const ushort4*)&in[srcbase + (size_t)(r + i * 16) * 1024 + c4];
  __syncthreads();
  size_t outbase = (size_t)bh * 524288 + (size_t)(dkt * 64) * 2048 + ct * 64;
  const float* ep = ebC + ((size_t)bh * 32 + ct) * 256 + dkt * 64;
#pragma unroll
  for (int i = 0; i < 4; ++i) {
    int dkl = r + i * 16;
    float e = WITHE ? ep[dkl] : 1.0f;
    ushort4 o;
    o.x = f2bf(bf2f(T[c4 + 0][dkl]) * e);
    o.y = f2bf(bf2f(T[c4 + 1][dkl]) * e);
    o.z = f2bf(bf2f(T[c4 + 2][dkl]) * e);
    o.w = f2bf(bf2f(T[c4 + 3][dkl]) * e);
    *(ushort4*)&outT[outbase + (size_t)dkl * 2048 + c4] = o;
  }
}

// ---------------------------------------------------------------------------
// u_gemm: per (bh,c,tile): UT_c[128dv x 128dk] = vT_slice @ khatT_slice^T,K=64
// ---------------------------------------------------------------------------
__global__ __launch_bounds__(256) void u_gemm(const unsigned short* __restrict__ khatT,
                                              const unsigned short* __restrict__ vT,
                                              unsigned short* __restrict__ UT) {
  __shared__ unsigned short As[128 * 64];
  __shared__ unsigned short Bs[128 * 64];
  int tid = threadIdx.x;
  int bid = blockIdx.x;
  int tile = bid & 3;
  int bhc = bid >> 2;  // bh*32 + c
  int bh = bhc >> 5, c = bhc & 31;
  int m0 = (tile >> 1) * 128, n0 = (tile & 1) * 128;
  const unsigned short* Ab = vT + (size_t)bh * 524288 + c * 64;     // rows=dv
  const unsigned short* Bb = khatT + (size_t)bh * 524288 + c * 64;  // rows=dk
  unsigned short* Cb = UT + (size_t)bhc * 65536;

  int lane = tid & 63;
  int w64 = tid & 192;
  int wid = tid >> 6;
  int wm = (wid >> 1) * 64, wn = (wid & 1) * 64;
  int fr = lane & 15, fq = lane >> 4;

  f32x4 acc[4][4] = {};

#pragma unroll
  for (int j = 0; j < 4; ++j) {
    int gl = j * 256 + tid;
    int row = gl >> 3;
    int gs = (gl & 7) ^ (row & 7);
    gload16(&Ab[(size_t)(m0 + row) * 2048 + gs * 8],
            &As[(size_t)(j * 256 + w64) * 8]);
    gload16(&Bb[(size_t)(n0 + row) * 2048 + gs * 8],
            &Bs[(size_t)(j * 256 + w64) * 8]);
  }
  __syncthreads();

#pragma unroll
  for (int ph = 0; ph < 2; ++ph) {
    bf16x8 af[4], bv[4];
#pragma unroll
    for (int i = 0; i < 4; ++i) {
      int ra = wm + i * 16 + fr;
      af[i] = *(const bf16x8*)&As[ra * 64 + (((ph * 4 + fq) ^ (ra & 7)) * 8)];
      int rb = wn + i * 16 + fr;
      bv[i] = *(const bf16x8*)&Bs[rb * 64 + (((ph * 4 + fq) ^ (rb & 7)) * 8)];
    }
#pragma unroll
    for (int i = 0; i < 4; ++i)
#pragma unroll
      for (int jj = 0; jj < 4; ++jj)
        acc[i][jj] = __builtin_amdgcn_mfma_f32_16x16x32_bf16(af[i], bv[jj],
                                                             acc[i][jj], 0, 0, 0);
  }

  int col = lane & 15;
  int rbase = (lane >> 4) * 4;
#pragma unroll
  for (int i = 0; i < 4; ++i)
#pragma unroll
    for (int j = 0; j < 4; ++j) {
      int n = n0 + wn + j * 16 + col;
#pragma unroll
      for (int r = 0; r < 4; ++r) {
        int m = m0 + wm + i * 16 + rbase + r;
        Cb[(size_t)m * 256 + n] = f2bf(acc[i][j][r]);
      }
    }
}

// ---------------------------------------------------------------------------
// hscan: in-place UT -> HT (chunk-start states, [dv][dk] layout).
// ---------------------------------------------------------------------------
__global__ __launch_bounds__(256) void hscan(unsigned short* __restrict__ UH,
                                             const float* __restrict__ ebC) {
  int bid = blockIdx.x;
  int bh = bid >> 8, dv = bid & 255;
  int tid = threadIdx.x;  // dk
  size_t base = ((size_t)bh * NCHK) * 65536 + (size_t)dv * 256 + tid;
  const float* ebb = ebC + (size_t)bh * NCHK * 256;
  float h = 0.0f;
  for (int c = 0; c < NCHK; ++c) {
    size_t a = base + (size_t)c * 65536;
    float u = bf2f(UH[a]);
    UH[a] = f2bf(h);
    h = ebb[c * 256 + tid] * h + u;
  }
}

// ---------------------------------------------------------------------------
// intra_mfma: per (bh,c): P = causal(q~ k~^T) via MFMA, park P bf16 in
// swizzled LDS, then O_intra = P @ V via MFMA (V from vT, B^T form).
// ---------------------------------------------------------------------------
__global__ __launch_bounds__(256) void intra_mfma(
    const unsigned short* __restrict__ qt, const unsigned short* __restrict__ kt,
    const unsigned short* __restrict__ vT, float* __restrict__ o) {
  __shared__ unsigned short QK[2][64 * 264];  // Qs, Ks ([64][264] pad rows)
  __shared__ unsigned short Sb[64 * 64];      // P bf16, XOR-swizzled
  unsigned short* Vs = &QK[0][0];             // overlay: [256][72] after phase1

  int bid = blockIdx.x;
  int c = bid & 31;
  int bh = bid >> 5;
  int b = bh >> 2, h = bh & 3;
  size_t rowbase = ((size_t)b * TT + c * 64) * 1024 + h * 256;
  size_t vtbase = (size_t)bh * 524288 + c * 64;
  int tid = threadIdx.x;
  int lane = tid & 63;
  int w = tid >> 6;
  int fr = lane & 15, fq = lane >> 4;

  // stage q~, k~ chunk tiles [64][256] -> [64][264]
#pragma unroll
  for (int i = 0; i < 8; ++i) {
    int g = tid + i * 256;       // 0..2047
    int row = g >> 5, gc = g & 31;
    *(bf16x8*)&QK[0][row * 264 + gc * 8] =
        *(const bf16x8*)&qt[rowbase + (size_t)row * 1024 + gc * 8];
    *(bf16x8*)&QK[1][row * 264 + gc * 8] =
        *(const bf16x8*)&kt[rowbase + (size_t)row * 1024 + gc * 8];
  }
  __syncthreads();

  // phase 1: P rows [w*16, w*16+16), cols all 64, K=256
  {
    f32x4 accs[4] = {};
#pragma unroll
    for (int ks = 0; ks < 8; ++ks) {
      bf16x8 af = *(const bf16x8*)&QK[0][(w * 16 + fr) * 264 + ks * 32 + fq * 8];
#pragma unroll
      for (int si = 0; si < 4; ++si) {
        bf16x8 bf_ = *(const bf16x8*)&QK[1][(si * 16 + fr) * 264 + ks * 32 + fq * 8];
        accs[si] = __builtin_amdgcn_mfma_f32_16x16x32_bf16(af, bf_, accs[si], 0, 0, 0);
      }
    }
#pragma unroll
    for (int si = 0; si < 4; ++si) {
#pragma unroll
      for (int r = 0; r < 4; ++r) {
        int t = w * 16 + fq * 4 + r;
        int s = si * 16 + fr;
        float val = (s <= t) ? accs[si][r] : 0.0f;
        int gS = s >> 3;
        Sb[t * 64 + ((gS ^ (t & 7)) * 8) + (s & 7)] = f2bf(val);
      }
    }
  }
  __syncthreads();

  // stage V slice [256 dv][64 s] from vT -> Vs [256][72]
#pragma unroll
  for (int i = 0; i < 8; ++i) {
    int g = tid + i * 256;       // 0..2047
    int dv = g >> 3, gc = g & 7;
    *(bf16x8*)&Vs[dv * 72 + gc * 8] =
        *(const bf16x8*)&vT[vtbase + (size_t)dv * 2048 + gc * 8];
  }
  __syncthreads();

  // phase 2: o[t][dv-panel w] = P @ V^T(form), K=64
  {
    int dv0 = w * 64;
    f32x4 acco[4][4] = {};
#pragma unroll
    for (int ks = 0; ks < 2; ++ks) {
      bf16x8 af[4], bv[4];
#pragma unroll
      for (int ti = 0; ti < 4; ++ti) {
        int t = ti * 16 + fr;
        af[ti] = *(const bf16x8*)&Sb[t * 64 + (((ks * 4 + fq) ^ (t & 7)) * 8)];
      }
#pragma unroll
      for (int nj = 0; nj < 4; ++nj)
        bv[nj] = *(const bf16x8*)&Vs[(dv0 + nj * 16 + fr) * 72 + ks * 32 + fq * 8];
#pragma unroll
      for (int ti = 0; ti < 4; ++ti)
#pragma unroll
        for (int nj = 0; nj < 4; ++nj)
          acco[ti][nj] = __builtin_amdgcn_mfma_f32_16x16x32_bf16(af[ti], bv[nj],
                                                                 acco[ti][nj], 0, 0, 0);
    }
#pragma unroll
    for (int ti = 0; ti < 4; ++ti)
#pragma unroll
      for (int nj = 0; nj < 4; ++nj)
#pragma unroll
        for (int r = 0; r < 4; ++r) {
          int t = ti * 16 + fq * 4 + r;
          int dv = dv0 + nj * 16 + fr;
          o[rowbase + (size_t)t * 1024 + dv] = acco[ti][nj][r];
        }
  }
}

// ---------------------------------------------------------------------------
// inter_mfma: per (bh,c): o += q~_chunk[64][256] @ H_c (HT [dv][dk] B^T form)
// ---------------------------------------------------------------------------
__global__ __launch_bounds__(256) void inter_mfma(
    const unsigned short* __restrict__ qt, const unsigned short* __restrict__ HT,
    float* __restrict__ o) {
  __shared__ unsigned short Qs[64 * 264];
  __shared__ unsigned short Hs[256 * 72];
  int bid = blockIdx.x;
  int c = bid & 31;
  int bh = bid >> 5;
  int b = bh >> 2, h = bh & 3;
  size_t rowbase = ((size_t)b * TT + c * 64) * 1024 + h * 256;
  size_t htbase = ((size_t)(bh * 32 + c)) * 65536;
  int tid = threadIdx.x;
  int lane = tid & 63;
  int w = tid >> 6;
  int fr = lane & 15, fq = lane >> 4;
  int dv0 = w * 64;

  // stage q~ chunk [64][256]
#pragma unroll
  for (int i = 0; i < 8; ++i) {
    int g = tid + i * 256;
    int row = g >> 5, gc = g & 31;
    *(bf16x8*)&Qs[row * 264 + gc * 8] =
        *(const bf16x8*)&qt[rowbase + (size_t)row * 1024 + gc * 8];
  }

  f32x4 acc[4][4] = {};
  for (int k4 = 0; k4 < 4; ++k4) {
    __syncthreads();
#pragma unroll
    for (int i = 0; i < 8; ++i) {
      int g = tid + i * 256;
      int dv = g >> 3, gc = g & 7;
      *(bf16x8*)&Hs[dv * 72 + gc * 8] =
          *(const bf16x8*)&HT[htbase + (size_t)dv * 256 + k4 * 64 + gc * 8];
    }
    __syncthreads();
#pragma unroll
    for (int ks = 0; ks < 2; ++ks) {
      bf16x8 af[4], bv[4];
#pragma unroll
      for (int ti = 0; ti < 4; ++ti)
        af[ti] = *(const bf16x8*)&Qs[(ti * 16 + fr) * 264 + k4 * 64 + ks * 32 + fq * 8];
#pragma unroll
      for (int nj = 0; nj < 4; ++nj)
        bv[nj] = *(const bf16x8*)&Hs[(dv0 + nj * 16 + fr) * 72 + ks * 32 + fq * 8];
#pragma unroll
      for (int ti = 0; ti < 4; ++ti)
#pragma unroll
        for (int nj = 0; nj < 4; ++nj)
          acc[ti][nj] = __builtin_amdgcn_mfma_f32_16x16x32_bf16(af[ti], bv[nj],
                                                                acc[ti][nj], 0, 0, 0);
    }
  }

#pragma unroll
  for (int ti = 0; ti < 4; ++ti)
#pragma unroll
    for (int nj = 0; nj < 4; ++nj)
#pragma unroll
      for (int r = 0; r < 4; ++r) {
        int t = ti * 16 + fq * 4 + r;
        int dv = dv0 + nj * 16 + fr;
        size_t a = rowbase + (size_t)t * 1024 + dv;
        o[a] += acc[ti][nj][r];
      }
}

// ---------------------------------------------------------------------------
// Gated RMSNorm: o f32, g bf16 -> og bf16
// ---------------------------------------------------------------------------
__global__ __launch_bounds__(256) void grms_kernel(const float* __restrict__ o,
                                                   const unsigned short* __restrict__ g,
                                                   const float* __restrict__ rw,
                                                   unsigned short* __restrict__ og) {
  size_t base = (size_t)blockIdx.x * 256;
  int tid = threadIdx.x;
  float ov = o[base + tid];
  float s = ov * ov;
#pragma unroll
  for (int off = 32; off > 0; off >>= 1) s += __shfl_down(s, off);
  __shared__ float red[4];
  int wid = tid >> 6;
  if ((tid & 63) == 0) red[wid] = s;
  __syncthreads();
  float ms = (red[0] + red[1] + red[2] + red[3]) * (1.0f / 256.0f);
  float gv = bf2f(g[base + tid]);
  float sw = gv / (1.0f + expf(-gv));
  og[base + tid] = f2bf(ov * rsqrtf(ms + 1e-5f) * rw[tid] * sw);
}

// ---------------------------------------------------------------------------
extern "C" void kernel_launch(void* const* d_in, const int* in_sizes, int n_in,
                              void* d_out, int out_size, void* d_ws,
                              size_t ws_size, hipStream_t stream) {
  const float* x = (const float*)d_in[0];
  const float* ln1_w = (const float*)d_in[1];
  const float* ln1_b = (const float*)d_in[2];
  const float* Wq = (const float*)d_in[3];
  const float* Wk = (const float*)d_in[4];
  const float* Wv = (const float*)d_in[5];
  const float* Wg = (const float*)d_in[6];
  const float* Wgk1 = (const float*)d_in[7];
  const float* Wgk2 = (const float*)d_in[8];
  const float* bgk2 = (const float*)d_in[9];
  const float* rms_w = (const float*)d_in[10];
  const float* Wo = (const float*)d_in[11];
  const float* ln2_w = (const float*)d_in[12];
  const float* ln2_b = (const float*)d_in[13];
  const float* W1 = (const float*)d_in[14];
  const float* b1 = (const float*)d_in[15];
  const float* W2 = (const float*)d_in[16];
  const float* b2 = (const float*)d_in[17];
  float* out = (float*)d_out;

  const size_t S = SS;  // 8388608 elements
  unsigned short* actb = (unsigned short*)d_ws;  // xn -> vT -> og/xn2
  unsigned short* qb = actb + S;                 // q~   (qkvg contiguous!)
  unsigned short* kb = qb + S;                   // k~
  unsigned short* vb = kb + S;                   // v
  unsigned short* gb = vb + S;                   // g
  unsigned short* gkb = gb + S;                  // gk -> khatT
  float* ofs = (float*)(gkb + S);                // o (f32, S)
  unsigned short* UH = (unsigned short*)(ofs + S);  // UT -> HT, 4S bf16
  float* ebC = (float*)(UH + 4 * S);             // 131072 f32
  unsigned short* Wqkvgt = (unsigned short*)(ebC + 131072);  // 4x 1M bf16
  unsigned short* Wot = Wqkvgt + 4194304;
  unsigned short* W1t = Wot + 1048576;
  unsigned short* W2t = W1t + 3145728;
  // overlays:
  unsigned short* khatT = gkb;   // after gate_chunk, gk dead
  unsigned short* vT = actb;     // after gk_kernel, xn dead
  float* x1 = (float*)kb;        // f32 S over kb+vb (dead after intra)
  unsigned short* hb = UH;       // MLP hidden 3S bf16 (UH dead after inter)

  dim3 blk(256);
  dim3 blk512(512);

  // 0. weight transposes (qkvg into one contiguous [4096][1024] block)
  transpose_cast<<<dim3(32, 32), blk, 0, stream>>>(Wq, Wqkvgt, 1024, 1024);
  transpose_cast<<<dim3(32, 32), blk, 0, stream>>>(Wk, Wqkvgt + 1048576, 1024, 1024);
  transpose_cast<<<dim3(32, 32), blk, 0, stream>>>(Wv, Wqkvgt + 2097152, 1024, 1024);
  transpose_cast<<<dim3(32, 32), blk, 0, stream>>>(Wg, Wqkvgt + 3145728, 1024, 1024);
  transpose_cast<<<dim3(32, 32), blk, 0, stream>>>(Wo, Wot, 1024, 1024);
  transpose_cast<<<dim3(96, 32), blk, 0, stream>>>(W1, W1t, 1024, 3072);
  transpose_cast<<<dim3(32, 96), blk, 0, stream>>>(W2, W2t, 3072, 1024);

  // 1. xn = LN(x)
  ln_kernel<<<RR, blk, 0, stream>>>(x, ln1_w, ln1_b, actb);

  // 2. merged q|k|v|g projection: N=4096, fan-out epilogue to qb..gb
  dim3 g4096(4096 / 256, RR / 256);
  gemm256<5, 1><<<g4096, blk512, 0, stream>>>(actb, Wqkvgt, nullptr, nullptr, qb,
                                              RR, 4096, 1024);

  // 3. gk -> gkb
  gk_kernel<<<RR, blk, 0, stream>>>(actb, Wgk1, Wgk2, bgk2, gkb);

  // 4. gate transforms (in-place q,k), ebC
  gate_chunk<<<BB * HH * NCHK, blk, 0, stream>>>(gkb, qb, kb, ebC);

  // 5. transposes: khatT (ebC folded) over gkb; vT over actb
  trans_kernel<1><<<16 * 32 * 4, blk, 0, stream>>>(kb, ebC, khatT);
  trans_kernel<0><<<16 * 32 * 4, blk, 0, stream>>>(vb, ebC, vT);

  // 6. UT_c = (khat^T v)^T (MFMA) -> UH ; in-place scan -> HT
  u_gemm<<<16 * NCHK * 4, blk, 0, stream>>>(khatT, vT, UH);
  hscan<<<16 * 256, blk, 0, stream>>>(UH, ebC);

  // 7. intra-chunk (MFMA) -> ofs ; inter adds q~ @ H_c (MFMA)
  intra_mfma<<<16 * NCHK, blk, 0, stream>>>(qb, kb, vT, ofs);
  inter_mfma<<<16 * NCHK, blk, 0, stream>>>(qb, UH, ofs);

  // 8. og = gated rmsnorm -> actb (vT dead)
  grms_kernel<<<RR * HH, blk, 0, stream>>>(ofs, gb, rms_w, actb);

  // 9. x1 = x + og @ Wo
  dim3 g1024(1024 / 256, RR / 256);
  gemm256<3, 0><<<g1024, blk512, 0, stream>>>(actb, Wot, nullptr, x, x1, RR, 1024, 1024);

  // 10. xn2 = LN(x1) -> actb
  ln_kernel<<<RR, blk, 0, stream>>>(x1, ln2_w, ln2_b, actb);

  // 11. h = (leaky_relu(xn2@W1+b1))^2 -> hb (over UH)
  dim3 g3072(3072 / 256, RR / 256);
  gemm256<2, 1><<<g3072, blk512, 0, stream>>>(actb, W1t, b1, nullptr, hb, RR, 3072, 1024);

  // 12. out = x1 + h @ W2 + b2
  gemm256<4, 0><<<g1024, blk512, 0, stream>>>(hb, W2t, b2, x1, out, RR, 1024, 3072);
}

// Round 9
// 445.201 us; speedup vs baseline: 1.1986x; 1.1986x over previous
//
#include <hip/hip_runtime.h>
#include <math.h>

// Problem constants
#define BB 4
#define TT 2048
#define DD 1024
#define HH 4
#define DK 256
#define DV 256
#define RR 8192
#define CHK 64
#define NCHK 32
#define SS ((size_t)RR * DD)

typedef __bf16 bf16x8 __attribute__((ext_vector_type(8)));
typedef float f32x4 __attribute__((ext_vector_type(4)));

static __device__ inline unsigned short f2bf(float f) {
  unsigned int u = __float_as_uint(f);
  unsigned int r = (u + 0x7fffu + ((u >> 16) & 1u)) >> 16;
  return (unsigned short)r;
}
static __device__ inline float bf2f(unsigned short h) {
  return __uint_as_float(((unsigned int)h) << 16);
}

// async global->LDS, 16B per lane; dest = wave-uniform base + lane*16
static __device__ __forceinline__ void gload16(const unsigned short* g,
                                               unsigned short* l) {
  __builtin_amdgcn_global_load_lds(
      (const __attribute__((address_space(1))) void*)g,
      (__attribute__((address_space(3))) void*)l, 16, 0, 0);
}

// ---------------------------------------------------------------------------
// LayerNorm: one block (256 thr) per row of D=1024. f32 in -> bf16 out.
// ---------------------------------------------------------------------------
__global__ __launch_bounds__(256) void ln_kernel(const float* __restrict__ x,
                                                 const float* __restrict__ w,
                                                 const float* __restrict__ b,
                                                 unsigned short* __restrict__ yb) {
  int row = blockIdx.x;
  const float* xr = x + (size_t)row * DD;
  unsigned short* ybr = yb + (size_t)row * DD;
  int tid = threadIdx.x;

  float4 v = ((const float4*)xr)[tid];
  float s = v.x + v.y + v.z + v.w;
  float ss = v.x * v.x + v.y * v.y + v.z * v.z + v.w * v.w;
#pragma unroll
  for (int o = 32; o > 0; o >>= 1) {
    s += __shfl_down(s, o);
    ss += __shfl_down(ss, o);
  }
  __shared__ float ls[4], lss[4];
  int wid = tid >> 6;
  if ((tid & 63) == 0) { ls[wid] = s; lss[wid] = ss; }
  __syncthreads();
  float sum = ls[0] + ls[1] + ls[2] + ls[3];
  float sumsq = lss[0] + lss[1] + lss[2] + lss[3];
  float mu = sum * (1.0f / DD);
  float var = sumsq * (1.0f / DD) - mu * mu;
  float rs = rsqrtf(var + 1e-5f);

  float4 wv = ((const float4*)w)[tid];
  float4 bv = ((const float4*)b)[tid];
  ushort4 ob;
  ob.x = f2bf((v.x - mu) * rs * wv.x + bv.x);
  ob.y = f2bf((v.y - mu) * rs * wv.y + bv.y);
  ob.z = f2bf((v.z - mu) * rs * wv.z + bv.z);
  ob.w = f2bf((v.w - mu) * rs * wv.w + bv.w);
  ((ushort4*)ybr)[tid] = ob;
}

// ---------------------------------------------------------------------------
// Weight transpose + cast: W [K,N] f32 -> Wt [N,K] bf16
// ---------------------------------------------------------------------------
__global__ __launch_bounds__(256) void transpose_cast(const float* __restrict__ W,
                                                      unsigned short* __restrict__ Wt,
                                                      int K, int N) {
  __shared__ float t[32][33];
  int k0 = blockIdx.y * 32, n0 = blockIdx.x * 32;
  int tid = threadIdx.x;
  int tx = tid & 31, ty = tid >> 5;  // ty 0..7
#pragma unroll
  for (int i = 0; i < 4; ++i)
    t[ty + i * 8][tx] = W[(size_t)(k0 + ty + i * 8) * N + n0 + tx];
  __syncthreads();
#pragma unroll
  for (int i = 0; i < 4; ++i)
    Wt[(size_t)(n0 + ty + i * 8) * K + k0 + tx] = f2bf(t[tx][ty + i * 8]);
}

// ---------------------------------------------------------------------------
// bf16 MFMA GEMM: C[M,N] = A[M,K] @ Bt[N,K]^T  (+epilogue)
// 128x128 tile, BK=64, double-buffered global_load_lds staging, XOR-swizzled
// LDS, XCD block swizzle. (R7 proven version, 755 TF.)
// EPI: 0 none, 2 +bias,(leaky)^2, 3 +res, 4 +bias+res,
//      5 proj fan-out: write bf16 to Cv[(n>>10)*SS + m*1024 + (n&1023)]
// ---------------------------------------------------------------------------
template <int EPI, int OUTBF>
__global__ __launch_bounds__(256) void gemm_bf16(
    const unsigned short* __restrict__ A,   // [M,K] bf16
    const unsigned short* __restrict__ Bt,  // [N,K] bf16
    const float* __restrict__ bias, const float* __restrict__ Res,
    void* __restrict__ Cv, int M, int N, int K) {
  __shared__ unsigned short As[2][128 * 64];  // [buf][row][64 bf16]
  __shared__ unsigned short Bs[2][128 * 64];
  int tid = threadIdx.x;
  // XCD-aware swizzle (nwg % 8 == 0)
  int nwg = gridDim.x * gridDim.y;
  int wg = blockIdx.y * gridDim.x + blockIdx.x;
  int cpx = nwg >> 3;
  wg = (wg & 7) * cpx + (wg >> 3);
  int m0 = (wg / gridDim.x) * 128, n0 = (wg % gridDim.x) * 128;
  int lane = tid & 63;
  int w64 = tid & 192;  // wave * 64
  int wid = tid >> 6;
  int wm = (wid >> 1) * 64, wn = (wid & 1) * 64;
  int fr = lane & 15, fq = lane >> 4;

  f32x4 acc[4][4] = {};

  auto STAGE = [&](int buf, int k0) {
#pragma unroll
    for (int j = 0; j < 4; ++j) {
      int gl = j * 256 + tid;           // granule 0..1023
      int row = gl >> 3;
      int gs = (gl & 7) ^ (row & 7);    // inverse-swizzled source granule
      gload16(&A[(size_t)(m0 + row) * K + k0 + gs * 8],
              &As[buf][(size_t)(j * 256 + w64) * 8]);
      gload16(&Bt[(size_t)(n0 + row) * K + k0 + gs * 8],
              &Bs[buf][(size_t)(j * 256 + w64) * 8]);
    }
  };

  STAGE(0, 0);
  asm volatile("s_waitcnt vmcnt(0)");
  __syncthreads();

  int cur = 0;
  for (int k0 = 0; k0 < K; k0 += 64) {
    if (k0 + 64 < K) STAGE(cur ^ 1, k0 + 64);  // prefetch next tile

#pragma unroll
    for (int ph = 0; ph < 2; ++ph) {
      bf16x8 af[4], bv[4];
#pragma unroll
      for (int i = 0; i < 4; ++i) {
        int ra = wm + i * 16 + fr;
        af[i] = *(const bf16x8*)&As[cur][ra * 64 + (((ph * 4 + fq) ^ (ra & 7)) * 8)];
        int rb = wn + i * 16 + fr;
        bv[i] = *(const bf16x8*)&Bs[cur][rb * 64 + (((ph * 4 + fq) ^ (rb & 7)) * 8)];
      }
#pragma unroll
      for (int i = 0; i < 4; ++i)
#pragma unroll
        for (int jj = 0; jj < 4; ++jj)
          acc[i][jj] = __builtin_amdgcn_mfma_f32_16x16x32_bf16(af[i], bv[jj],
                                                               acc[i][jj], 0, 0, 0);
    }
    __syncthreads();  // drains vmcnt -> prefetched tile visible; buffers safe
    cur ^= 1;
  }

  // epilogue: C/D layout col=lane&15, row=(lane>>4)*4+r
  int col = lane & 15;
  int rbase = (lane >> 4) * 4;
#pragma unroll
  for (int i = 0; i < 4; ++i) {
#pragma unroll
    for (int j = 0; j < 4; ++j) {
      int n = n0 + wn + j * 16 + col;
      float bvv = (EPI == 2 || EPI == 4) ? bias[n] : 0.0f;
#pragma unroll
      for (int r = 0; r < 4; ++r) {
        int m = m0 + wm + i * 16 + rbase + r;
        float vv = acc[i][j][r] + bvv;
        if (EPI == 2) {
          float t = vv > 0.0f ? vv : 0.01f * vv;
          vv = t * t;
        }
        if (EPI == 3 || EPI == 4) vv += Res[(size_t)m * N + n];
        if (EPI == 5) {
          ((unsigned short*)Cv)[(size_t)(n >> 10) * SS + (size_t)m * 1024 +
                                (n & 1023)] = f2bf(vv);
        } else if (OUTBF) {
          ((unsigned short*)Cv)[(size_t)m * N + n] = f2bf(vv);
        } else {
          ((float*)Cv)[(size_t)m * N + n] = vv;
        }
      }
    }
  }
}

// ---------------------------------------------------------------------------
// Low-rank forget gate -> LOG gate gk = log_sigmoid(z)/16 (bf16 in/out)
// ---------------------------------------------------------------------------
__global__ __launch_bounds__(256) void gk_kernel(const unsigned short* __restrict__ xn,
                                                 const float* __restrict__ Wgk1,
                                                 const float* __restrict__ Wgk2,
                                                 const float* __restrict__ bgk2,
                                                 unsigned short* __restrict__ gk) {
  int row = blockIdx.x;
  const unsigned short* xr = xn + (size_t)row * DD;
  int tid = threadIdx.x;

  float t16[16];
#pragma unroll
  for (int j = 0; j < 16; ++j) t16[j] = 0.0f;

#pragma unroll
  for (int dd = 0; dd < 4; ++dd) {
    int d = tid + dd * 256;
    float xv = bf2f(xr[d]);
    const float4* wrow = (const float4*)(Wgk1 + (size_t)d * 16);
#pragma unroll
    for (int q = 0; q < 4; ++q) {
      float4 wq = wrow[q];
      t16[q * 4 + 0] += xv * wq.x;
      t16[q * 4 + 1] += xv * wq.y;
      t16[q * 4 + 2] += xv * wq.z;
      t16[q * 4 + 3] += xv * wq.w;
    }
  }
#pragma unroll
  for (int j = 0; j < 16; ++j) {
    float s = t16[j];
#pragma unroll
    for (int o = 32; o > 0; o >>= 1) s += __shfl_down(s, o);
    t16[j] = s;
  }
  __shared__ float tmp[4][16];
  __shared__ float tf[16];
  int wid = tid >> 6;
  if ((tid & 63) == 0) {
#pragma unroll
    for (int j = 0; j < 16; ++j) tmp[wid][j] = t16[j];
  }
  __syncthreads();
  if (tid < 16) tf[tid] = tmp[0][tid] + tmp[1][tid] + tmp[2][tid] + tmp[3][tid];
  __syncthreads();

  float tl[16];
#pragma unroll
  for (int j = 0; j < 16; ++j) tl[j] = tf[j];

#pragma unroll
  for (int jj = 0; jj < 4; ++jj) {
    int n = tid * 4 + jj;
    float z = bgk2[n];
#pragma unroll
    for (int j = 0; j < 16; ++j) z += tl[j] * Wgk2[j * 1024 + n];
    float ls = fminf(z, 0.0f) - log1pf(expf(-fabsf(z)));
    gk[(size_t)row * 1024 + n] = f2bf(ls * (1.0f / 16.0f));
  }
}

// ---------------------------------------------------------------------------
// gate_chunk: per (b,h,chunk) block, 256 thr (one dk col each), bf16 in-place:
// q <- q*exp(cum)*scale; k <- k*exp(-cum); ebC = exp(cum_end) out (f32).
// ---------------------------------------------------------------------------
__global__ __launch_bounds__(256) void gate_chunk(const unsigned short* __restrict__ gk,
                                                  unsigned short* __restrict__ q,
                                                  unsigned short* __restrict__ k,
                                                  float* __restrict__ ebC) {
  int bid = blockIdx.x;
  int c = bid & 31;
  int h = (bid >> 5) & 3;
  int b = bid >> 7;
  int tid = threadIdx.x;
  size_t base = ((size_t)b * TT + c * CHK) * 1024 + h * 256 + tid;

  const float scale = 0.0625f;
  float cum = 0.0f;
  for (int t = 0; t < CHK; ++t) {
    size_t a = base + (size_t)t * 1024;
    cum += bf2f(gk[a]);
    q[a] = f2bf(bf2f(q[a]) * expf(cum) * scale);
    k[a] = f2bf(bf2f(k[a]) * expf(-cum));
  }
  ebC[((b * 4 + h) * NCHK + c) * 256 + tid] = expf(cum);
}

// ---------------------------------------------------------------------------
// trans_kernel: [B*T, H*256] slice -> T-major [bh][256][2048]; WITHE folds ebC
// ---------------------------------------------------------------------------
template <int WITHE>
__global__ __launch_bounds__(256) void trans_kernel(const unsigned short* __restrict__ in,
                                                    const float* __restrict__ ebC,
                                                    unsigned short* __restrict__ outT) {
  __shared__ unsigned short T[64][68];
  int bid = blockIdx.x;
  int dkt = bid & 3;
  int ct = (bid >> 2) & 31;
  int bh = bid >> 7;
  int b = bh >> 2, h = bh & 3;
  int tid = threadIdx.x;
  int r = tid >> 4;            // 0..15
  int c4 = (tid & 15) * 4;
  size_t srcbase = ((size_t)b * TT + ct * 64) * 1024 + h * 256 + dkt * 64;
#pragma unroll
  for (int i = 0; i < 4; ++i)
    *(ushort4*)&T[r + i * 16][c4] =
        *(const ushort4*)&in[srcbase + (size_t)(r + i * 16) * 1024 + c4];
  __syncthreads();
  size_t outbase = (size_t)bh * 524288 + (size_t)(dkt * 64) * 2048 + ct * 64;
  const float* ep = ebC + ((size_t)bh * 32 + ct) * 256 + dkt * 64;
#pragma unroll
  for (int i = 0; i < 4; ++i) {
    int dkl = r + i * 16;
    float e = WITHE ? ep[dkl] : 1.0f;
    ushort4 o;
    o.x = f2bf(bf2f(T[c4 + 0][dkl]) * e);
    o.y = f2bf(bf2f(T[c4 + 1][dkl]) * e);
    o.z = f2bf(bf2f(T[c4 + 2][dkl]) * e);
    o.w = f2bf(bf2f(T[c4 + 3][dkl]) * e);
    *(ushort4*)&outT[outbase + (size_t)dkl * 2048 + c4] = o;
  }
}

// ---------------------------------------------------------------------------
// u_gemm: per (bh,c,tile): UT_c[128dv x 128dk] = vT_slice @ khatT_slice^T,K=64
// ---------------------------------------------------------------------------
__global__ __launch_bounds__(256) void u_gemm(const unsigned short* __restrict__ khatT,
                                              const unsigned short* __restrict__ vT,
                                              unsigned short* __restrict__ UT) {
  __shared__ unsigned short As[128 * 64];
  __shared__ unsigned short Bs[128 * 64];
  int tid = threadIdx.x;
  int bid = blockIdx.x;
  int tile = bid & 3;
  int bhc = bid >> 2;  // bh*32 + c
  int bh = bhc >> 5, c = bhc & 31;
  int m0 = (tile >> 1) * 128, n0 = (tile & 1) * 128;
  const unsigned short* Ab = vT + (size_t)bh * 524288 + c * 64;     // rows=dv
  const unsigned short* Bb = khatT + (size_t)bh * 524288 + c * 64;  // rows=dk
  unsigned short* Cb = UT + (size_t)bhc * 65536;

  int lane = tid & 63;
  int w64 = tid & 192;
  int wid = tid >> 6;
  int wm = (wid >> 1) * 64, wn = (wid & 1) * 64;
  int fr = lane & 15, fq = lane >> 4;

  f32x4 acc[4][4] = {};

#pragma unroll
  for (int j = 0; j < 4; ++j) {
    int gl = j * 256 + tid;
    int row = gl >> 3;
    int gs = (gl & 7) ^ (row & 7);
    gload16(&Ab[(size_t)(m0 + row) * 2048 + gs * 8],
            &As[(size_t)(j * 256 + w64) * 8]);
    gload16(&Bb[(size_t)(n0 + row) * 2048 + gs * 8],
            &Bs[(size_t)(j * 256 + w64) * 8]);
  }
  __syncthreads();

#pragma unroll
  for (int ph = 0; ph < 2; ++ph) {
    bf16x8 af[4], bv[4];
#pragma unroll
    for (int i = 0; i < 4; ++i) {
      int ra = wm + i * 16 + fr;
      af[i] = *(const bf16x8*)&As[ra * 64 + (((ph * 4 + fq) ^ (ra & 7)) * 8)];
      int rb = wn + i * 16 + fr;
      bv[i] = *(const bf16x8*)&Bs[rb * 64 + (((ph * 4 + fq) ^ (rb & 7)) * 8)];
    }
#pragma unroll
    for (int i = 0; i < 4; ++i)
#pragma unroll
      for (int jj = 0; jj < 4; ++jj)
        acc[i][jj] = __builtin_amdgcn_mfma_f32_16x16x32_bf16(af[i], bv[jj],
                                                             acc[i][jj], 0, 0, 0);
  }

  int col = lane & 15;
  int rbase = (lane >> 4) * 4;
#pragma unroll
  for (int i = 0; i < 4; ++i)
#pragma unroll
    for (int j = 0; j < 4; ++j) {
      int n = n0 + wn + j * 16 + col;
#pragma unroll
      for (int r = 0; r < 4; ++r) {
        int m = m0 + wm + i * 16 + rbase + r;
        Cb[(size_t)m * 256 + n] = f2bf(acc[i][j][r]);
      }
    }
}

// ---------------------------------------------------------------------------
// hscan: in-place UT -> HT (chunk-start states, [dv][dk] layout).
// ---------------------------------------------------------------------------
__global__ __launch_bounds__(256) void hscan(unsigned short* __restrict__ UH,
                                             const float* __restrict__ ebC) {
  int bid = blockIdx.x;
  int bh = bid >> 8, dv = bid & 255;
  int tid = threadIdx.x;  // dk
  size_t base = ((size_t)bh * NCHK) * 65536 + (size_t)dv * 256 + tid;
  const float* ebb = ebC + (size_t)bh * NCHK * 256;
  float h = 0.0f;
  for (int c = 0; c < NCHK; ++c) {
    size_t a = base + (size_t)c * 65536;
    float u = bf2f(UH[a]);
    UH[a] = f2bf(h);
    h = ebb[c * 256 + tid] * h + u;
  }
}

// ---------------------------------------------------------------------------
// attn_fused: per (bh,c), 4 waves. Fuses:
//   phase1: P = causal(q~ k~^T) via MFMA -> Sb (bf16, XOR-swizzled)
//   phase2: acc = P @ V (V from vT)                [wave owns 64-dv panel]
//   inter:  acc += q~ @ H_c (HT [dv][dk], 4 K-slices)
//   epilogue: gated RMSNorm (cross-wave sumsq reduce) -> og bf16
// ---------------------------------------------------------------------------
__global__ __launch_bounds__(256) void attn_fused(
    const unsigned short* __restrict__ qt, const unsigned short* __restrict__ kt,
    const unsigned short* __restrict__ vT, const unsigned short* __restrict__ HT,
    const unsigned short* __restrict__ gp, const float* __restrict__ rw,
    unsigned short* __restrict__ og) {
  __shared__ unsigned short Qs[64 * 264];    // q~ tile, alive whole kernel
  __shared__ unsigned short KVH[256 * 72];   // union: Ks[64][264] / Vs / Hs
  __shared__ unsigned short Sb[64 * 64];     // P bf16, XOR-swizzled
  __shared__ float red[64][4];               // per-row sumsq partials per wave

  int bid = blockIdx.x;
  int c = bid & 31;
  int bh = bid >> 5;
  int b = bh >> 2, h = bh & 3;
  size_t rowbase = ((size_t)b * TT + c * 64) * 1024 + h * 256;
  size_t vtbase = (size_t)bh * 524288 + c * 64;
  size_t htbase = ((size_t)(bh * 32 + c)) * 65536;
  int tid = threadIdx.x;
  int lane = tid & 63;
  int w = tid >> 6;
  int fr = lane & 15, fq = lane >> 4;

  // stage q~ -> Qs, k~ -> KVH ([64][264] layout)
#pragma unroll
  for (int i = 0; i < 8; ++i) {
    int gg = tid + i * 256;
    int row = gg >> 5, gc = gg & 31;
    *(bf16x8*)&Qs[row * 264 + gc * 8] =
        *(const bf16x8*)&qt[rowbase + (size_t)row * 1024 + gc * 8];
    *(bf16x8*)&KVH[row * 264 + gc * 8] =
        *(const bf16x8*)&kt[rowbase + (size_t)row * 1024 + gc * 8];
  }
  __syncthreads();

  // phase 1: P rows [w*16, w*16+16), cols all 64, K=256
  {
    f32x4 accs[4] = {};
#pragma unroll
    for (int ks = 0; ks < 8; ++ks) {
      bf16x8 af = *(const bf16x8*)&Qs[(w * 16 + fr) * 264 + ks * 32 + fq * 8];
#pragma unroll
      for (int si = 0; si < 4; ++si) {
        bf16x8 bf_ = *(const bf16x8*)&KVH[(si * 16 + fr) * 264 + ks * 32 + fq * 8];
        accs[si] = __builtin_amdgcn_mfma_f32_16x16x32_bf16(af, bf_, accs[si], 0, 0, 0);
      }
    }
#pragma unroll
    for (int si = 0; si < 4; ++si) {
#pragma unroll
      for (int r = 0; r < 4; ++r) {
        int t = w * 16 + fq * 4 + r;
        int s = si * 16 + fr;
        float val = (s <= t) ? accs[si][r] : 0.0f;
        Sb[t * 64 + (((s >> 3) ^ (t & 7)) * 8) + (s & 7)] = f2bf(val);
      }
    }
  }
  __syncthreads();  // Sb complete; Ks dead

  // stage V slice [256 dv][64 s] over KVH
#pragma unroll
  for (int i = 0; i < 8; ++i) {
    int gg = tid + i * 256;
    int dv = gg >> 3, gc = gg & 7;
    *(bf16x8*)&KVH[dv * 72 + gc * 8] =
        *(const bf16x8*)&vT[vtbase + (size_t)dv * 2048 + gc * 8];
  }
  __syncthreads();

  int dv0 = w * 64;
  f32x4 acc[4][4] = {};

  // phase 2: acc = P @ V (K=64)
#pragma unroll
  for (int ks = 0; ks < 2; ++ks) {
    bf16x8 af[4], bv[4];
#pragma unroll
    for (int ti = 0; ti < 4; ++ti) {
      int t = ti * 16 + fr;
      af[ti] = *(const bf16x8*)&Sb[t * 64 + (((ks * 4 + fq) ^ (t & 7)) * 8)];
    }
#pragma unroll
    for (int nj = 0; nj < 4; ++nj)
      bv[nj] = *(const bf16x8*)&KVH[(dv0 + nj * 16 + fr) * 72 + ks * 32 + fq * 8];
#pragma unroll
    for (int ti = 0; ti < 4; ++ti)
#pragma unroll
      for (int nj = 0; nj < 4; ++nj)
        acc[ti][nj] = __builtin_amdgcn_mfma_f32_16x16x32_bf16(af[ti], bv[nj],
                                                              acc[ti][nj], 0, 0, 0);
  }

  // inter: acc += q~ @ H_c, K=256 in 4 slices of 64
  for (int k4 = 0; k4 < 4; ++k4) {
    __syncthreads();  // previous KVH readers done
#pragma unroll
    for (int i = 0; i < 8; ++i) {
      int gg = tid + i * 256;
      int dv = gg >> 3, gc = gg & 7;
      *(bf16x8*)&KVH[dv * 72 + gc * 8] =
          *(const bf16x8*)&HT[htbase + (size_t)dv * 256 + k4 * 64 + gc * 8];
    }
    __syncthreads();
#pragma unroll
    for (int ks = 0; ks < 2; ++ks) {
      bf16x8 af[4], bv[4];
#pragma unroll
      for (int ti = 0; ti < 4; ++ti)
        af[ti] = *(const bf16x8*)&Qs[(ti * 16 + fr) * 264 + k4 * 64 + ks * 32 + fq * 8];
#pragma unroll
      for (int nj = 0; nj < 4; ++nj)
        bv[nj] = *(const bf16x8*)&KVH[(dv0 + nj * 16 + fr) * 72 + ks * 32 + fq * 8];
#pragma unroll
      for (int ti = 0; ti < 4; ++ti)
#pragma unroll
        for (int nj = 0; nj < 4; ++nj)
          acc[ti][nj] = __builtin_amdgcn_mfma_f32_16x16x32_bf16(af[ti], bv[nj],
                                                                acc[ti][nj], 0, 0, 0);
    }
  }

  // fused gated RMSNorm epilogue
  float rstd[4][4];
#pragma unroll
  for (int ti = 0; ti < 4; ++ti) {
#pragma unroll
    for (int r = 0; r < 4; ++r) {
      float s = 0.0f;
#pragma unroll
      for (int nj = 0; nj < 4; ++nj) {
        float v = acc[ti][nj][r];
        s += v * v;
      }
      // reduce over fr (lane bits 0..3): sumsq over wave's 64-dv panel
      s += __shfl_xor(s, 1);
      s += __shfl_xor(s, 2);
      s += __shfl_xor(s, 4);
      s += __shfl_xor(s, 8);
      rstd[ti][r] = s;  // panel partial for row t
    }
  }
  if (fr == 0) {
#pragma unroll
    for (int ti = 0; ti < 4; ++ti)
#pragma unroll
      for (int r = 0; r < 4; ++r)
        red[ti * 16 + fq * 4 + r][w] = rstd[ti][r];
  }
  __syncthreads();
#pragma unroll
  for (int ti = 0; ti < 4; ++ti) {
#pragma unroll
    for (int r = 0; r < 4; ++r) {
      int t = ti * 16 + fq * 4 + r;
      float tot = red[t][0] + red[t][1] + red[t][2] + red[t][3];
      rstd[ti][r] = rsqrtf(tot * (1.0f / 256.0f) + 1e-5f);
    }
  }
#pragma unroll
  for (int ti = 0; ti < 4; ++ti) {
#pragma unroll
    for (int nj = 0; nj < 4; ++nj) {
      int dv = dv0 + nj * 16 + fr;
      float rwv = rw[dv];
#pragma unroll
      for (int r = 0; r < 4; ++r) {
        int t = ti * 16 + fq * 4 + r;
        float gv = bf2f(gp[rowbase + (size_t)t * 1024 + dv]);
        float sw = gv / (1.0f + expf(-gv));
        og[rowbase + (size_t)t * 1024 + dv] =
            f2bf(acc[ti][nj][r] * rstd[ti][r] * rwv * sw);
      }
    }
  }
}

// ---------------------------------------------------------------------------
extern "C" void kernel_launch(void* const* d_in, const int* in_sizes, int n_in,
                              void* d_out, int out_size, void* d_ws,
                              size_t ws_size, hipStream_t stream) {
  const float* x = (const float*)d_in[0];
  const float* ln1_w = (const float*)d_in[1];
  const float* ln1_b = (const float*)d_in[2];
  const float* Wq = (const float*)d_in[3];
  const float* Wk = (const float*)d_in[4];
  const float* Wv = (const float*)d_in[5];
  const float* Wg = (const float*)d_in[6];
  const float* Wgk1 = (const float*)d_in[7];
  const float* Wgk2 = (const float*)d_in[8];
  const float* bgk2 = (const float*)d_in[9];
  const float* rms_w = (const float*)d_in[10];
  const float* Wo = (const float*)d_in[11];
  const float* ln2_w = (const float*)d_in[12];
  const float* ln2_b = (const float*)d_in[13];
  const float* W1 = (const float*)d_in[14];
  const float* b1 = (const float*)d_in[15];
  const float* W2 = (const float*)d_in[16];
  const float* b2 = (const float*)d_in[17];
  float* out = (float*)d_out;

  const size_t S = SS;  // 8388608 elements
  unsigned short* actb = (unsigned short*)d_ws;  // xn -> vT -> xn2
  unsigned short* qb = actb + S;                 // q~   (qkvg contiguous)
  unsigned short* kb = qb + S;                   // k~
  unsigned short* vb = kb + S;                   // v
  unsigned short* gb = vb + S;                   // g
  unsigned short* gkb = gb + S;                  // gk -> khatT (overlay)
  unsigned short* ogb = gkb + S;                 // og (S bf16); +S spare
  unsigned short* UH = ogb + 2 * S;              // UT -> HT, 4S bf16
  float* ebC = (float*)(UH + 4 * S);             // 131072 f32
  unsigned short* Wqkvgt = (unsigned short*)(ebC + 131072);  // 4x 1M bf16
  unsigned short* Wot = Wqkvgt + 4194304;
  unsigned short* W1t = Wot + 1048576;
  unsigned short* W2t = W1t + 3145728;
  // overlays:
  unsigned short* khatT = gkb;   // after gate_chunk, gk dead
  unsigned short* vT = actb;     // after gk_kernel, xn dead
  float* x1 = (float*)kb;        // f32 S over kb+vb (dead after attn)
  unsigned short* hb = UH;       // MLP hidden 3S bf16 (HT dead after attn)

  dim3 blk(256);

  // 0. weight transposes (qkvg into one contiguous [4096][1024] block)
  transpose_cast<<<dim3(32, 32), blk, 0, stream>>>(Wq, Wqkvgt, 1024, 1024);
  transpose_cast<<<dim3(32, 32), blk, 0, stream>>>(Wk, Wqkvgt + 1048576, 1024, 1024);
  transpose_cast<<<dim3(32, 32), blk, 0, stream>>>(Wv, Wqkvgt + 2097152, 1024, 1024);
  transpose_cast<<<dim3(32, 32), blk, 0, stream>>>(Wg, Wqkvgt + 3145728, 1024, 1024);
  transpose_cast<<<dim3(32, 32), blk, 0, stream>>>(Wo, Wot, 1024, 1024);
  transpose_cast<<<dim3(96, 32), blk, 0, stream>>>(W1, W1t, 1024, 3072);
  transpose_cast<<<dim3(32, 96), blk, 0, stream>>>(W2, W2t, 3072, 1024);

  // 1. xn = LN(x)
  ln_kernel<<<RR, blk, 0, stream>>>(x, ln1_w, ln1_b, actb);

  // 2. merged q|k|v|g projection: N=4096, fan-out epilogue to qb..gb
  dim3 g4096(4096 / 128, RR / 128);
  gemm_bf16<5, 1><<<g4096, blk, 0, stream>>>(actb, Wqkvgt, nullptr, nullptr, qb,
                                             RR, 4096, 1024);

  // 3. gk -> gkb
  gk_kernel<<<RR, blk, 0, stream>>>(actb, Wgk1, Wgk2, bgk2, gkb);

  // 4. gate transforms (in-place q,k), ebC
  gate_chunk<<<BB * HH * NCHK, blk, 0, stream>>>(gkb, qb, kb, ebC);

  // 5. transposes: khatT (ebC folded) over gkb; vT over actb
  trans_kernel<1><<<16 * 32 * 4, blk, 0, stream>>>(kb, ebC, khatT);
  trans_kernel<0><<<16 * 32 * 4, blk, 0, stream>>>(vb, ebC, vT);

  // 6. UT_c = (khat^T v)^T (MFMA) -> UH ; in-place scan -> HT
  u_gemm<<<16 * NCHK * 4, blk, 0, stream>>>(khatT, vT, UH);
  hscan<<<16 * 256, blk, 0, stream>>>(UH, ebC);

  // 7. fused intra + inter + gated rmsnorm -> ogb (bf16)
  attn_fused<<<16 * NCHK, blk, 0, stream>>>(qb, kb, vT, UH, gb, rms_w, ogb);

  // 8. x1 = x + og @ Wo
  dim3 g1024(1024 / 128, RR / 128);
  gemm_bf16<3, 0><<<g1024, blk, 0, stream>>>(ogb, Wot, nullptr, x, x1, RR, 1024, 1024);

  // 9. xn2 = LN(x1) -> actb (vT dead)
  ln_kernel<<<RR, blk, 0, stream>>>(x1, ln2_w, ln2_b, actb);

  // 10. h = (leaky_relu(xn2@W1+b1))^2 -> hb (over UH)
  dim3 g3072(3072 / 128, RR / 128);
  gemm_bf16<2, 1><<<g3072, blk, 0, stream>>>(actb, W1t, b1, nullptr, hb, RR, 3072, 1024);

  // 11. out = x1 + h @ W2 + b2
  gemm_bf16<4, 0><<<g1024, blk, 0, stream>>>(hb, W2t, b2, x1, out, RR, 1024, 3072);
}

// Round 10
// 426.115 us; speedup vs baseline: 1.2523x; 1.0448x over previous
//
#include <hip/hip_runtime.h>
#include <math.h>

// Problem constants
#define BB 4
#define TT 2048
#define DD 1024
#define HH 4
#define DK 256
#define DV 256
#define RR 8192
#define CHK 64
#define NCHK 32
#define SS ((size_t)RR * DD)

typedef __bf16 bf16x8 __attribute__((ext_vector_type(8)));
typedef float f32x4 __attribute__((ext_vector_type(4)));

static __device__ inline unsigned short f2bf(float f) {
  unsigned int u = __float_as_uint(f);
  unsigned int r = (u + 0x7fffu + ((u >> 16) & 1u)) >> 16;
  return (unsigned short)r;
}
static __device__ inline float bf2f(unsigned short h) {
  return __uint_as_float(((unsigned int)h) << 16);
}

// async global->LDS, 16B per lane; dest = wave-uniform base + lane*16
static __device__ __forceinline__ void gload16(const unsigned short* g,
                                               unsigned short* l) {
  __builtin_amdgcn_global_load_lds(
      (const __attribute__((address_space(1))) void*)g,
      (__attribute__((address_space(3))) void*)l, 16, 0, 0);
}

// ---------------------------------------------------------------------------
// LayerNorm: one block (256 thr) per row of D=1024. f32 in -> bf16 out.
// ---------------------------------------------------------------------------
__global__ __launch_bounds__(256) void ln_kernel(const float* __restrict__ x,
                                                 const float* __restrict__ w,
                                                 const float* __restrict__ b,
                                                 unsigned short* __restrict__ yb) {
  int row = blockIdx.x;
  const float* xr = x + (size_t)row * DD;
  unsigned short* ybr = yb + (size_t)row * DD;
  int tid = threadIdx.x;

  float4 v = ((const float4*)xr)[tid];
  float s = v.x + v.y + v.z + v.w;
  float ss = v.x * v.x + v.y * v.y + v.z * v.z + v.w * v.w;
#pragma unroll
  for (int o = 32; o > 0; o >>= 1) {
    s += __shfl_down(s, o);
    ss += __shfl_down(ss, o);
  }
  __shared__ float ls[4], lss[4];
  int wid = tid >> 6;
  if ((tid & 63) == 0) { ls[wid] = s; lss[wid] = ss; }
  __syncthreads();
  float sum = ls[0] + ls[1] + ls[2] + ls[3];
  float sumsq = lss[0] + lss[1] + lss[2] + lss[3];
  float mu = sum * (1.0f / DD);
  float var = sumsq * (1.0f / DD) - mu * mu;
  float rs = rsqrtf(var + 1e-5f);

  float4 wv = ((const float4*)w)[tid];
  float4 bv = ((const float4*)b)[tid];
  ushort4 ob;
  ob.x = f2bf((v.x - mu) * rs * wv.x + bv.x);
  ob.y = f2bf((v.y - mu) * rs * wv.y + bv.y);
  ob.z = f2bf((v.z - mu) * rs * wv.z + bv.z);
  ob.w = f2bf((v.w - mu) * rs * wv.w + bv.w);
  ((ushort4*)ybr)[tid] = ob;
}

// ---------------------------------------------------------------------------
// Weight transpose + cast: W [K,N] f32 -> Wt [N,K] bf16
// ---------------------------------------------------------------------------
__global__ __launch_bounds__(256) void transpose_cast(const float* __restrict__ W,
                                                      unsigned short* __restrict__ Wt,
                                                      int K, int N) {
  __shared__ float t[32][33];
  int k0 = blockIdx.y * 32, n0 = blockIdx.x * 32;
  int tid = threadIdx.x;
  int tx = tid & 31, ty = tid >> 5;  // ty 0..7
#pragma unroll
  for (int i = 0; i < 4; ++i)
    t[ty + i * 8][tx] = W[(size_t)(k0 + ty + i * 8) * N + n0 + tx];
  __syncthreads();
#pragma unroll
  for (int i = 0; i < 4; ++i)
    Wt[(size_t)(n0 + ty + i * 8) * K + k0 + tx] = f2bf(t[tx][ty + i * 8]);
}

// batched 1024x1024 transpose (5 matrices in one launch)
struct P5 {
  const float* w[5];
  unsigned short* o[5];
};
__global__ __launch_bounds__(256) void transpose5(P5 p) {
  __shared__ float t[32][33];
  int z = blockIdx.z;
  const float* W = p.w[z];
  unsigned short* Wt = p.o[z];
  int k0 = blockIdx.y * 32, n0 = blockIdx.x * 32;
  int tid = threadIdx.x;
  int tx = tid & 31, ty = tid >> 5;
#pragma unroll
  for (int i = 0; i < 4; ++i)
    t[ty + i * 8][tx] = W[(size_t)(k0 + ty + i * 8) * 1024 + n0 + tx];
  __syncthreads();
#pragma unroll
  for (int i = 0; i < 4; ++i)
    Wt[(size_t)(n0 + ty + i * 8) * 1024 + k0 + tx] = f2bf(t[tx][ty + i * 8]);
}

// ---------------------------------------------------------------------------
// bf16 MFMA GEMM: C[M,N] = A[M,K] @ Bt[N,K]^T  (+epilogue)
// 128x128 tile, BK=64, double-buffered global_load_lds staging, XOR-swizzled
// LDS, XCD block swizzle. (R7 proven version, 755 TF.)
// EPI: 0 none, 2 +bias,(leaky)^2, 3 +res, 4 +bias+res,
//      5 proj fan-out: write bf16 to Cv[(n>>10)*SS + m*1024 + (n&1023)]
// ---------------------------------------------------------------------------
template <int EPI, int OUTBF>
__global__ __launch_bounds__(256) void gemm_bf16(
    const unsigned short* __restrict__ A,   // [M,K] bf16
    const unsigned short* __restrict__ Bt,  // [N,K] bf16
    const float* __restrict__ bias, const float* __restrict__ Res,
    void* __restrict__ Cv, int M, int N, int K) {
  __shared__ unsigned short As[2][128 * 64];  // [buf][row][64 bf16]
  __shared__ unsigned short Bs[2][128 * 64];
  int tid = threadIdx.x;
  // XCD-aware swizzle (nwg % 8 == 0)
  int nwg = gridDim.x * gridDim.y;
  int wg = blockIdx.y * gridDim.x + blockIdx.x;
  int cpx = nwg >> 3;
  wg = (wg & 7) * cpx + (wg >> 3);
  int m0 = (wg / gridDim.x) * 128, n0 = (wg % gridDim.x) * 128;
  int lane = tid & 63;
  int w64 = tid & 192;  // wave * 64
  int wid = tid >> 6;
  int wm = (wid >> 1) * 64, wn = (wid & 1) * 64;
  int fr = lane & 15, fq = lane >> 4;

  f32x4 acc[4][4] = {};

  auto STAGE = [&](int buf, int k0) {
#pragma unroll
    for (int j = 0; j < 4; ++j) {
      int gl = j * 256 + tid;           // granule 0..1023
      int row = gl >> 3;
      int gs = (gl & 7) ^ (row & 7);    // inverse-swizzled source granule
      gload16(&A[(size_t)(m0 + row) * K + k0 + gs * 8],
              &As[buf][(size_t)(j * 256 + w64) * 8]);
      gload16(&Bt[(size_t)(n0 + row) * K + k0 + gs * 8],
              &Bs[buf][(size_t)(j * 256 + w64) * 8]);
    }
  };

  STAGE(0, 0);
  asm volatile("s_waitcnt vmcnt(0)");
  __syncthreads();

  int cur = 0;
  for (int k0 = 0; k0 < K; k0 += 64) {
    if (k0 + 64 < K) STAGE(cur ^ 1, k0 + 64);  // prefetch next tile

#pragma unroll
    for (int ph = 0; ph < 2; ++ph) {
      bf16x8 af[4], bv[4];
#pragma unroll
      for (int i = 0; i < 4; ++i) {
        int ra = wm + i * 16 + fr;
        af[i] = *(const bf16x8*)&As[cur][ra * 64 + (((ph * 4 + fq) ^ (ra & 7)) * 8)];
        int rb = wn + i * 16 + fr;
        bv[i] = *(const bf16x8*)&Bs[cur][rb * 64 + (((ph * 4 + fq) ^ (rb & 7)) * 8)];
      }
#pragma unroll
      for (int i = 0; i < 4; ++i)
#pragma unroll
        for (int jj = 0; jj < 4; ++jj)
          acc[i][jj] = __builtin_amdgcn_mfma_f32_16x16x32_bf16(af[i], bv[jj],
                                                               acc[i][jj], 0, 0, 0);
    }
    __syncthreads();  // drains vmcnt -> prefetched tile visible; buffers safe
    cur ^= 1;
  }

  // epilogue: C/D layout col=lane&15, row=(lane>>4)*4+r
  int col = lane & 15;
  int rbase = (lane >> 4) * 4;
#pragma unroll
  for (int i = 0; i < 4; ++i) {
#pragma unroll
    for (int j = 0; j < 4; ++j) {
      int n = n0 + wn + j * 16 + col;
      float bvv = (EPI == 2 || EPI == 4) ? bias[n] : 0.0f;
#pragma unroll
      for (int r = 0; r < 4; ++r) {
        int m = m0 + wm + i * 16 + rbase + r;
        float vv = acc[i][j][r] + bvv;
        if (EPI == 2) {
          float t = vv > 0.0f ? vv : 0.01f * vv;
          vv = t * t;
        }
        if (EPI == 3 || EPI == 4) vv += Res[(size_t)m * N + n];
        if (EPI == 5) {
          ((unsigned short*)Cv)[(size_t)(n >> 10) * SS + (size_t)m * 1024 +
                                (n & 1023)] = f2bf(vv);
        } else if (OUTBF) {
          ((unsigned short*)Cv)[(size_t)m * N + n] = f2bf(vv);
        } else {
          ((float*)Cv)[(size_t)m * N + n] = vv;
        }
      }
    }
  }
}

// ---------------------------------------------------------------------------
// Low-rank forget gate -> LOG gate gk = log_sigmoid(z)/16
// 16 rows per block; xn + Wgk1(bf16) staged in LDS; Wgk2 amortized 16x via L2.
// ---------------------------------------------------------------------------
__global__ __launch_bounds__(256) void gk_kernel(const unsigned short* __restrict__ xn,
                                                 const float* __restrict__ Wgk1,
                                                 const float* __restrict__ Wgk2,
                                                 const float* __restrict__ bgk2,
                                                 unsigned short* __restrict__ gk) {
  __shared__ unsigned short Xs[16 * 1024];  // 32KB: xn rows, later out tile
  __shared__ unsigned short W1s[1024 * 16]; // 32KB: Wgk1 bf16
  __shared__ float Ts[16][16];
  int r0 = blockIdx.x * 16;
  int tid = threadIdx.x;

  // stage xn 16 rows (ushort4-coalesced)
#pragma unroll
  for (int i = 0; i < 16; ++i) {
    int idx = tid + i * 256;   // ushort4 idx 0..4095
    ((ushort4*)Xs)[idx] = ((const ushort4*)(xn + (size_t)r0 * 1024))[idx];
  }
  // stage Wgk1 -> bf16
#pragma unroll
  for (int i = 0; i < 16; ++i) {
    int idx = tid + i * 256;   // float4 idx 0..4095
    float4 w = ((const float4*)Wgk1)[idx];
    ushort4 hh;
    hh.x = f2bf(w.x); hh.y = f2bf(w.y); hh.z = f2bf(w.z); hh.w = f2bf(w.w);
    ((ushort4*)W1s)[idx] = hh;
  }
  __syncthreads();

  // phase 1: Ts[r][16] = xn_row @ Wgk1. thread (r=tid>>4, part=tid&15)
  {
    int r = tid >> 4, part = tid & 15;
    float t16[16];
#pragma unroll
    for (int j = 0; j < 16; ++j) t16[j] = 0.0f;
    for (int dd = 0; dd < 64; ++dd) {
      int d = dd * 16 + part;  // part-interleaved to avoid LDS bank pile-up
      float xv = bf2f(Xs[r * 1024 + d]);
      const ushort4* wr = (const ushort4*)&W1s[d * 16];
#pragma unroll
      for (int q4 = 0; q4 < 4; ++q4) {
        ushort4 w = wr[q4];
        t16[q4 * 4 + 0] += xv * bf2f(w.x);
        t16[q4 * 4 + 1] += xv * bf2f(w.y);
        t16[q4 * 4 + 2] += xv * bf2f(w.z);
        t16[q4 * 4 + 3] += xv * bf2f(w.w);
      }
    }
#pragma unroll
    for (int j = 0; j < 16; ++j) {
      float s = t16[j];
      s += __shfl_xor(s, 1);
      s += __shfl_xor(s, 2);
      s += __shfl_xor(s, 4);
      s += __shfl_xor(s, 8);
      t16[j] = s;
    }
    if (part == 0) {
#pragma unroll
      for (int j = 0; j < 16; ++j) Ts[r][j] = t16[j];
    }
  }
  __syncthreads();  // also: all Xs reads done -> reusable as out tile

  // phase 2: z[r][n] for n = tid*4..+3, all 16 rows -> Xs (bf16 out tile)
  {
    float w2[16][4];
#pragma unroll
    for (int j = 0; j < 16; ++j) {
      float4 wv = *(const float4*)&Wgk2[(size_t)j * 1024 + tid * 4];
      w2[j][0] = wv.x; w2[j][1] = wv.y; w2[j][2] = wv.z; w2[j][3] = wv.w;
    }
    float4 bv = *(const float4*)&bgk2[tid * 4];
    float bb[4] = {bv.x, bv.y, bv.z, bv.w};
#pragma unroll
    for (int r = 0; r < 16; ++r) {
      ushort4 outv;
      unsigned short* op = (unsigned short*)&outv;
#pragma unroll
      for (int jj = 0; jj < 4; ++jj) {
        float z = bb[jj];
#pragma unroll
        for (int j = 0; j < 16; ++j) z += Ts[r][j] * w2[j][jj];
        float lsg = fminf(z, 0.0f) - log1pf(expf(-fabsf(z)));
        op[jj] = f2bf(lsg * (1.0f / 16.0f));
      }
      *(ushort4*)&Xs[r * 1024 + tid * 4] = outv;
    }
  }
  __syncthreads();
  // coalesced copy-out
#pragma unroll
  for (int i = 0; i < 16; ++i) {
    int idx = tid + i * 256;
    ((ushort4*)(gk + (size_t)r0 * 1024))[idx] = ((const ushort4*)Xs)[idx];
  }
}

// ---------------------------------------------------------------------------
// gate_chunk: per (b,h,chunk) block, 256 thr (one dk col each).
// Preload all 64 gk -> registers (pipelined), cumsum, then independent
// transform iterations. ebC = exp(cum_end).
// ---------------------------------------------------------------------------
__global__ __launch_bounds__(256) void gate_chunk(const unsigned short* __restrict__ gk,
                                                  unsigned short* __restrict__ q,
                                                  unsigned short* __restrict__ k,
                                                  float* __restrict__ ebC) {
  int bid = blockIdx.x;
  int c = bid & 31;
  int h = (bid >> 5) & 3;
  int b = bid >> 7;
  int tid = threadIdx.x;
  size_t base = ((size_t)b * TT + c * CHK) * 1024 + h * 256 + tid;

  float cums[64];
#pragma unroll
  for (int t = 0; t < 64; ++t) cums[t] = bf2f(gk[base + (size_t)t * 1024]);
  float cum = 0.0f;
#pragma unroll
  for (int t = 0; t < 64; ++t) {
    cum += cums[t];
    cums[t] = cum;
  }
  ebC[((b * 4 + h) * NCHK + c) * 256 + tid] = expf(cum);

  const float scale = 0.0625f;
#pragma unroll
  for (int t = 0; t < 64; ++t) {
    size_t a = base + (size_t)t * 1024;
    q[a] = f2bf(bf2f(q[a]) * expf(cums[t]) * scale);
    k[a] = f2bf(bf2f(k[a]) * expf(-cums[t]));
  }
}

// ---------------------------------------------------------------------------
// trans_kernel: [B*T, H*256] slice -> T-major [bh][256][2048]; WITHE folds ebC
// ---------------------------------------------------------------------------
template <int WITHE>
__global__ __launch_bounds__(256) void trans_kernel(const unsigned short* __restrict__ in,
                                                    const float* __restrict__ ebC,
                                                    unsigned short* __restrict__ outT) {
  __shared__ unsigned short T[64][68];
  int bid = blockIdx.x;
  int dkt = bid & 3;
  int ct = (bid >> 2) & 31;
  int bh = bid >> 7;
  int b = bh >> 2, h = bh & 3;
  int tid = threadIdx.x;
  int r = tid >> 4;            // 0..15
  int c4 = (tid & 15) * 4;
  size_t srcbase = ((size_t)b * TT + ct * 64) * 1024 + h * 256 + dkt * 64;
#pragma unroll
  for (int i = 0; i < 4; ++i)
    *(ushort4*)&T[r + i * 16][c4] =
        *(const ushort4*)&in[srcbase + (size_t)(r + i * 16) * 1024 + c4];
  __syncthreads();
  size_t outbase = (size_t)bh * 524288 + (size_t)(dkt * 64) * 2048 + ct * 64;
  const float* ep = ebC + ((size_t)bh * 32 + ct) * 256 + dkt * 64;
#pragma unroll
  for (int i = 0; i < 4; ++i) {
    int dkl = r + i * 16;
    float e = WITHE ? ep[dkl] : 1.0f;
    ushort4 o;
    o.x = f2bf(bf2f(T[c4 + 0][dkl]) * e);
    o.y = f2bf(bf2f(T[c4 + 1][dkl]) * e);
    o.z = f2bf(bf2f(T[c4 + 2][dkl]) * e);
    o.w = f2bf(bf2f(T[c4 + 3][dkl]) * e);
    *(ushort4*)&outT[outbase + (size_t)dkl * 2048 + c4] = o;
  }
}

// ---------------------------------------------------------------------------
// u_gemm: per (bh,c,tile): UT_c[128dv x 128dk] = vT_slice @ khatT_slice^T,K=64
// ---------------------------------------------------------------------------
__global__ __launch_bounds__(256) void u_gemm(const unsigned short* __restrict__ khatT,
                                              const unsigned short* __restrict__ vT,
                                              unsigned short* __restrict__ UT) {
  __shared__ unsigned short As[128 * 64];
  __shared__ unsigned short Bs[128 * 64];
  int tid = threadIdx.x;
  int bid = blockIdx.x;
  int tile = bid & 3;
  int bhc = bid >> 2;  // bh*32 + c
  int bh = bhc >> 5, c = bhc & 31;
  int m0 = (tile >> 1) * 128, n0 = (tile & 1) * 128;
  const unsigned short* Ab = vT + (size_t)bh * 524288 + c * 64;     // rows=dv
  const unsigned short* Bb = khatT + (size_t)bh * 524288 + c * 64;  // rows=dk
  unsigned short* Cb = UT + (size_t)bhc * 65536;

  int lane = tid & 63;
  int w64 = tid & 192;
  int wid = tid >> 6;
  int wm = (wid >> 1) * 64, wn = (wid & 1) * 64;
  int fr = lane & 15, fq = lane >> 4;

  f32x4 acc[4][4] = {};

#pragma unroll
  for (int j = 0; j < 4; ++j) {
    int gl = j * 256 + tid;
    int row = gl >> 3;
    int gs = (gl & 7) ^ (row & 7);
    gload16(&Ab[(size_t)(m0 + row) * 2048 + gs * 8],
            &As[(size_t)(j * 256 + w64) * 8]);
    gload16(&Bb[(size_t)(n0 + row) * 2048 + gs * 8],
            &Bs[(size_t)(j * 256 + w64) * 8]);
  }
  __syncthreads();

#pragma unroll
  for (int ph = 0; ph < 2; ++ph) {
    bf16x8 af[4], bv[4];
#pragma unroll
    for (int i = 0; i < 4; ++i) {
      int ra = wm + i * 16 + fr;
      af[i] = *(const bf16x8*)&As[ra * 64 + (((ph * 4 + fq) ^ (ra & 7)) * 8)];
      int rb = wn + i * 16 + fr;
      bv[i] = *(const bf16x8*)&Bs[rb * 64 + (((ph * 4 + fq) ^ (rb & 7)) * 8)];
    }
#pragma unroll
    for (int i = 0; i < 4; ++i)
#pragma unroll
      for (int jj = 0; jj < 4; ++jj)
        acc[i][jj] = __builtin_amdgcn_mfma_f32_16x16x32_bf16(af[i], bv[jj],
                                                             acc[i][jj], 0, 0, 0);
  }

  int col = lane & 15;
  int rbase = (lane >> 4) * 4;
#pragma unroll
  for (int i = 0; i < 4; ++i)
#pragma unroll
    for (int j = 0; j < 4; ++j) {
      int n = n0 + wn + j * 16 + col;
#pragma unroll
      for (int r = 0; r < 4; ++r) {
        int m = m0 + wm + i * 16 + rbase + r;
        Cb[(size_t)m * 256 + n] = f2bf(acc[i][j][r]);
      }
    }
}

// ---------------------------------------------------------------------------
// hscan: in-place UT -> HT. Preload all 32 u + e, then register scan.
// ---------------------------------------------------------------------------
__global__ __launch_bounds__(256) void hscan(unsigned short* __restrict__ UH,
                                             const float* __restrict__ ebC) {
  int bid = blockIdx.x;
  int bh = bid >> 8, dv = bid & 255;
  int tid = threadIdx.x;  // dk
  size_t base = ((size_t)bh * NCHK) * 65536 + (size_t)dv * 256 + tid;
  const float* ebb = ebC + (size_t)bh * NCHK * 256 + tid;

  float u[32], e[32];
#pragma unroll
  for (int c = 0; c < 32; ++c) u[c] = bf2f(UH[base + (size_t)c * 65536]);
#pragma unroll
  for (int c = 0; c < 32; ++c) e[c] = ebb[c * 256];
  float h = 0.0f;
#pragma unroll
  for (int c = 0; c < 32; ++c) {
    UH[base + (size_t)c * 65536] = f2bf(h);
    h = e[c] * h + u[c];
  }
}

// ---------------------------------------------------------------------------
// attn_fused: per (bh,c), 4 waves. intra + inter + gated RMSNorm -> og bf16
// ---------------------------------------------------------------------------
__global__ __launch_bounds__(256) void attn_fused(
    const unsigned short* __restrict__ qt, const unsigned short* __restrict__ kt,
    const unsigned short* __restrict__ vT, const unsigned short* __restrict__ HT,
    const unsigned short* __restrict__ gp, const float* __restrict__ rw,
    unsigned short* __restrict__ og) {
  __shared__ unsigned short Qs[64 * 264];    // q~ tile, alive whole kernel
  __shared__ unsigned short KVH[256 * 72];   // union: Ks[64][264] / Vs / Hs
  __shared__ unsigned short Sb[64 * 64];     // P bf16, XOR-swizzled
  __shared__ float red[64][4];               // per-row sumsq partials per wave

  int bid = blockIdx.x;
  int c = bid & 31;
  int bh = bid >> 5;
  int b = bh >> 2, h = bh & 3;
  size_t rowbase = ((size_t)b * TT + c * 64) * 1024 + h * 256;
  size_t vtbase = (size_t)bh * 524288 + c * 64;
  size_t htbase = ((size_t)(bh * 32 + c)) * 65536;
  int tid = threadIdx.x;
  int lane = tid & 63;
  int w = tid >> 6;
  int fr = lane & 15, fq = lane >> 4;

  // stage q~ -> Qs, k~ -> KVH ([64][264] layout)
#pragma unroll
  for (int i = 0; i < 8; ++i) {
    int gg = tid + i * 256;
    int row = gg >> 5, gc = gg & 31;
    *(bf16x8*)&Qs[row * 264 + gc * 8] =
        *(const bf16x8*)&qt[rowbase + (size_t)row * 1024 + gc * 8];
    *(bf16x8*)&KVH[row * 264 + gc * 8] =
        *(const bf16x8*)&kt[rowbase + (size_t)row * 1024 + gc * 8];
  }
  __syncthreads();

  // phase 1: P rows [w*16, w*16+16), cols all 64, K=256
  {
    f32x4 accs[4] = {};
#pragma unroll
    for (int ks = 0; ks < 8; ++ks) {
      bf16x8 af = *(const bf16x8*)&Qs[(w * 16 + fr) * 264 + ks * 32 + fq * 8];
#pragma unroll
      for (int si = 0; si < 4; ++si) {
        bf16x8 bf_ = *(const bf16x8*)&KVH[(si * 16 + fr) * 264 + ks * 32 + fq * 8];
        accs[si] = __builtin_amdgcn_mfma_f32_16x16x32_bf16(af, bf_, accs[si], 0, 0, 0);
      }
    }
#pragma unroll
    for (int si = 0; si < 4; ++si) {
#pragma unroll
      for (int r = 0; r < 4; ++r) {
        int t = w * 16 + fq * 4 + r;
        int s = si * 16 + fr;
        float val = (s <= t) ? accs[si][r] : 0.0f;
        Sb[t * 64 + (((s >> 3) ^ (t & 7)) * 8) + (s & 7)] = f2bf(val);
      }
    }
  }
  __syncthreads();  // Sb complete; Ks dead

  // stage V slice [256 dv][64 s] over KVH
#pragma unroll
  for (int i = 0; i < 8; ++i) {
    int gg = tid + i * 256;
    int dv = gg >> 3, gc = gg & 7;
    *(bf16x8*)&KVH[dv * 72 + gc * 8] =
        *(const bf16x8*)&vT[vtbase + (size_t)dv * 2048 + gc * 8];
  }
  __syncthreads();

  int dv0 = w * 64;
  f32x4 acc[4][4] = {};

  // phase 2: acc = P @ V (K=64)
#pragma unroll
  for (int ks = 0; ks < 2; ++ks) {
    bf16x8 af[4], bv[4];
#pragma unroll
    for (int ti = 0; ti < 4; ++ti) {
      int t = ti * 16 + fr;
      af[ti] = *(const bf16x8*)&Sb[t * 64 + (((ks * 4 + fq) ^ (t & 7)) * 8)];
    }
#pragma unroll
    for (int nj = 0; nj < 4; ++nj)
      bv[nj] = *(const bf16x8*)&KVH[(dv0 + nj * 16 + fr) * 72 + ks * 32 + fq * 8];
#pragma unroll
    for (int ti = 0; ti < 4; ++ti)
#pragma unroll
      for (int nj = 0; nj < 4; ++nj)
        acc[ti][nj] = __builtin_amdgcn_mfma_f32_16x16x32_bf16(af[ti], bv[nj],
                                                              acc[ti][nj], 0, 0, 0);
  }

  // inter: acc += q~ @ H_c, K=256 in 4 slices of 64
  for (int k4 = 0; k4 < 4; ++k4) {
    __syncthreads();  // previous KVH readers done
#pragma unroll
    for (int i = 0; i < 8; ++i) {
      int gg = tid + i * 256;
      int dv = gg >> 3, gc = gg & 7;
      *(bf16x8*)&KVH[dv * 72 + gc * 8] =
          *(const bf16x8*)&HT[htbase + (size_t)dv * 256 + k4 * 64 + gc * 8];
    }
    __syncthreads();
#pragma unroll
    for (int ks = 0; ks < 2; ++ks) {
      bf16x8 af[4], bv[4];
#pragma unroll
      for (int ti = 0; ti < 4; ++ti)
        af[ti] = *(const bf16x8*)&Qs[(ti * 16 + fr) * 264 + k4 * 64 + ks * 32 + fq * 8];
#pragma unroll
      for (int nj = 0; nj < 4; ++nj)
        bv[nj] = *(const bf16x8*)&KVH[(dv0 + nj * 16 + fr) * 72 + ks * 32 + fq * 8];
#pragma unroll
      for (int ti = 0; ti < 4; ++ti)
#pragma unroll
        for (int nj = 0; nj < 4; ++nj)
          acc[ti][nj] = __builtin_amdgcn_mfma_f32_16x16x32_bf16(af[ti], bv[nj],
                                                                acc[ti][nj], 0, 0, 0);
    }
  }

  // fused gated RMSNorm epilogue
  float rstd[4][4];
#pragma unroll
  for (int ti = 0; ti < 4; ++ti) {
#pragma unroll
    for (int r = 0; r < 4; ++r) {
      float s = 0.0f;
#pragma unroll
      for (int nj = 0; nj < 4; ++nj) {
        float v = acc[ti][nj][r];
        s += v * v;
      }
      s += __shfl_xor(s, 1);
      s += __shfl_xor(s, 2);
      s += __shfl_xor(s, 4);
      s += __shfl_xor(s, 8);
      rstd[ti][r] = s;
    }
  }
  if (fr == 0) {
#pragma unroll
    for (int ti = 0; ti < 4; ++ti)
#pragma unroll
      for (int r = 0; r < 4; ++r)
        red[ti * 16 + fq * 4 + r][w] = rstd[ti][r];
  }
  __syncthreads();
#pragma unroll
  for (int ti = 0; ti < 4; ++ti) {
#pragma unroll
    for (int r = 0; r < 4; ++r) {
      int t = ti * 16 + fq * 4 + r;
      float tot = red[t][0] + red[t][1] + red[t][2] + red[t][3];
      rstd[ti][r] = rsqrtf(tot * (1.0f / 256.0f) + 1e-5f);
    }
  }
#pragma unroll
  for (int ti = 0; ti < 4; ++ti) {
#pragma unroll
    for (int nj = 0; nj < 4; ++nj) {
      int dv = dv0 + nj * 16 + fr;
      float rwv = rw[dv];
#pragma unroll
      for (int r = 0; r < 4; ++r) {
        int t = ti * 16 + fq * 4 + r;
        float gv = bf2f(gp[rowbase + (size_t)t * 1024 + dv]);
        float sw = gv / (1.0f + expf(-gv));
        og[rowbase + (size_t)t * 1024 + dv] =
            f2bf(acc[ti][nj][r] * rstd[ti][r] * rwv * sw);
      }
    }
  }
}

// ---------------------------------------------------------------------------
extern "C" void kernel_launch(void* const* d_in, const int* in_sizes, int n_in,
                              void* d_out, int out_size, void* d_ws,
                              size_t ws_size, hipStream_t stream) {
  const float* x = (const float*)d_in[0];
  const float* ln1_w = (const float*)d_in[1];
  const float* ln1_b = (const float*)d_in[2];
  const float* Wq = (const float*)d_in[3];
  const float* Wk = (const float*)d_in[4];
  const float* Wv = (const float*)d_in[5];
  const float* Wg = (const float*)d_in[6];
  const float* Wgk1 = (const float*)d_in[7];
  const float* Wgk2 = (const float*)d_in[8];
  const float* bgk2 = (const float*)d_in[9];
  const float* rms_w = (const float*)d_in[10];
  const float* Wo = (const float*)d_in[11];
  const float* ln2_w = (const float*)d_in[12];
  const float* ln2_b = (const float*)d_in[13];
  const float* W1 = (const float*)d_in[14];
  const float* b1 = (const float*)d_in[15];
  const float* W2 = (const float*)d_in[16];
  const float* b2 = (const float*)d_in[17];
  float* out = (float*)d_out;

  const size_t S = SS;  // 8388608 elements
  unsigned short* actb = (unsigned short*)d_ws;  // xn -> vT -> xn2
  unsigned short* qb = actb + S;                 // q~   (qkvg contiguous)
  unsigned short* kb = qb + S;                   // k~
  unsigned short* vb = kb + S;                   // v
  unsigned short* gb = vb + S;                   // g
  unsigned short* gkb = gb + S;                  // gk -> khatT (overlay)
  unsigned short* ogb = gkb + S;                 // og (S bf16); +S spare
  unsigned short* UH = ogb + 2 * S;              // UT -> HT, 4S bf16
  float* ebC = (float*)(UH + 4 * S);             // 131072 f32
  unsigned short* Wqkvgt = (unsigned short*)(ebC + 131072);  // 4x 1M bf16
  unsigned short* Wot = Wqkvgt + 4194304;
  unsigned short* W1t = Wot + 1048576;
  unsigned short* W2t = W1t + 3145728;
  // overlays:
  unsigned short* khatT = gkb;   // after gate_chunk, gk dead
  unsigned short* vT = actb;     // after gk_kernel, xn dead
  float* x1 = (float*)kb;        // f32 S over kb+vb (dead after attn)
  unsigned short* hb = UH;       // MLP hidden 3S bf16 (HT dead after attn)

  dim3 blk(256);

  // 0. weight transposes: five 1024^2 in one launch; W1, W2 separate
  P5 p5;
  p5.w[0] = Wq;  p5.o[0] = Wqkvgt;
  p5.w[1] = Wk;  p5.o[1] = Wqkvgt + 1048576;
  p5.w[2] = Wv;  p5.o[2] = Wqkvgt + 2097152;
  p5.w[3] = Wg;  p5.o[3] = Wqkvgt + 3145728;
  p5.w[4] = Wo;  p5.o[4] = Wot;
  transpose5<<<dim3(32, 32, 5), blk, 0, stream>>>(p5);
  transpose_cast<<<dim3(96, 32), blk, 0, stream>>>(W1, W1t, 1024, 3072);
  transpose_cast<<<dim3(32, 96), blk, 0, stream>>>(W2, W2t, 3072, 1024);

  // 1. xn = LN(x)
  ln_kernel<<<RR, blk, 0, stream>>>(x, ln1_w, ln1_b, actb);

  // 2. merged q|k|v|g projection: N=4096, fan-out epilogue to qb..gb
  dim3 g4096(4096 / 128, RR / 128);
  gemm_bf16<5, 1><<<g4096, blk, 0, stream>>>(actb, Wqkvgt, nullptr, nullptr, qb,
                                             RR, 4096, 1024);

  // 3. gk -> gkb (16 rows/block)
  gk_kernel<<<RR / 16, blk, 0, stream>>>(actb, Wgk1, Wgk2, bgk2, gkb);

  // 4. gate transforms (in-place q,k), ebC
  gate_chunk<<<BB * HH * NCHK, blk, 0, stream>>>(gkb, qb, kb, ebC);

  // 5. transposes: khatT (ebC folded) over gkb; vT over actb
  trans_kernel<1><<<16 * 32 * 4, blk, 0, stream>>>(kb, ebC, khatT);
  trans_kernel<0><<<16 * 32 * 4, blk, 0, stream>>>(vb, ebC, vT);

  // 6. UT_c = (khat^T v)^T (MFMA) -> UH ; in-place scan -> HT
  u_gemm<<<16 * NCHK * 4, blk, 0, stream>>>(khatT, vT, UH);
  hscan<<<16 * 256, blk, 0, stream>>>(UH, ebC);

  // 7. fused intra + inter + gated rmsnorm -> ogb (bf16)
  attn_fused<<<16 * NCHK, blk, 0, stream>>>(qb, kb, vT, UH, gb, rms_w, ogb);

  // 8. x1 = x + og @ Wo
  dim3 g1024(1024 / 128, RR / 128);
  gemm_bf16<3, 0><<<g1024, blk, 0, stream>>>(ogb, Wot, nullptr, x, x1, RR, 1024, 1024);

  // 9. xn2 = LN(x1) -> actb (vT dead)
  ln_kernel<<<RR, blk, 0, stream>>>(x1, ln2_w, ln2_b, actb);

  // 10. h = (leaky_relu(xn2@W1+b1))^2 -> hb (over UH)
  dim3 g3072(3072 / 128, RR / 128);
  gemm_bf16<2, 1><<<g3072, blk, 0, stream>>>(actb, W1t, b1, nullptr, hb, RR, 3072, 1024);

  // 11. out = x1 + h @ W2 + b2
  gemm_bf16<4, 0><<<g1024, blk, 0, stream>>>(hb, W2t, b2, x1, out, RR, 1024, 3072);
}